// Round 2
// baseline (849.521 us; speedup 1.0000x reference)
//
#include <hip/hip_runtime.h>

#define BB 4096
#define SS 512
#define NG 256     // 4*HID gate columns
#define BT 16      // buffer row dimension (MFMA M); rows BTL..15 are dead-zero
#define BTL 8      // LIVE batch rows per workgroup (grid = 512 = 2 blocks/CU)
#define NT 512     // 8 waves: 0-3 compute (MFMA+cell), 4-7 service (head/stage/flush)
#define CH 32      // time-chunk length
#define HSTR 68    // hbuf row stride (shorts)
#define PSTR 16    // pcx row stride (shorts): slots 0..11 real, 12..15 zero
#define SBSTR 264  // sbias row stride (floats), overlaid on pcx
#define OSTR 33    // obuf row stride (floats)

typedef __bf16 bf16_t;
typedef bf16_t bf16x8 __attribute__((ext_vector_type(8)));
typedef float  f32x4  __attribute__((ext_vector_type(4)));

__device__ __forceinline__ unsigned short f2bf(float x) {
    union { float f; unsigned u; } q{x};
    unsigned r = (q.u + 0x7fffu + ((q.u >> 16) & 1u)) >> 16;
    return (unsigned short)r;
}
__device__ __forceinline__ float bf2f(unsigned short s) {
    union { unsigned u; float f; } q{((unsigned)s) << 16};
    return q.f;
}
#define LOG2E 1.4426950408889634f
__device__ __forceinline__ float frcp_(float x)  { return __builtin_amdgcn_rcpf(x); }
__device__ __forceinline__ float fexp2_(float x) { return __builtin_amdgcn_exp2f(x); }
__device__ __forceinline__ float flog2_(float x) { return __builtin_amdgcn_logf(x); }
__device__ __forceinline__ float softplus_(float x){ return x > 20.0f ? x : 0.6931471805599453f * flog2_(1.0f + fexp2_(LOG2E * x)); }

// K-slot layout (96): 0..63 = h, 64 = prev, 65..74 = cov, 75 = prev residual, 76..95 = 0.
// Gate columns pre-scaled: i,f,o by -log2e; g by -2log2e, so the cell needs no pre-mul:
//   sigma(x) = rcp(1+exp2(y)),  tanh(x) = 2*rcp(1+exp2(z)) - 1.
// Waves 0-3: wave wv owns all 4 gates for units 16wv..16wv+15; cell lane-local.
// Wave 4: output head via MFMA. Waves 4-7: chunk staging/flush. One barrier/step.
//
// TWO BLOCKS PER CU (grid 512, BTL=8 live rows): independent barriers let the
// co-resident block's waves fill this block's stall cycles (LDS latency, trans
// chain tails, barrier drain) — waves at DIFFERENT phases, unlike the failed
// round-1 same-barrier symmetrization. Rows 8..15 of all buffers are permanent
// zeros; dead-row cell math is finite and confined (never stored to out).
__global__ __launch_bounds__(NT)
void deepar_kernel(const float* __restrict__ target, const float* __restrict__ cov,
                   const int* __restrict__ cats, const float* __restrict__ scale,
                   const float* __restrict__ emb0, const float* __restrict__ emb1,
                   const float* __restrict__ emb2, const float* __restrict__ emb3,
                   const float* __restrict__ w_ih, const float* __restrict__ w_hh,
                   const float* __restrict__ bias, const float* __restrict__ w_out,
                   const float* __restrict__ b_out, float* __restrict__ out)
{
    // pcx (2*32*16*16 shorts = 32768 B) overlays sbias(16896 B)+sx(4352 B) scratch
    __shared__ __attribute__((aligned(16))) unsigned char smemA[2 * CH * BT * PSTR * 2];
    __shared__ __attribute__((aligned(16))) unsigned short hbuf[2][BT][HSTR]; //  4352 B
    __shared__ float obuf[2][CH][OSTR];                                       //  8448 B
    __shared__ float inv_s[BT], scl_s[BT];

    unsigned short* pcx   = (unsigned short*)smemA;
    float*          sbias = (float*)smemA;
    float*          sx    = (float*)(smemA + BT * SBSTR * 4);

    const int tid  = threadIdx.x;
    const int b0   = blockIdx.x * BTL;
    const int lane = tid & 63;
    const int wv   = tid >> 6;
    const int qd   = lane >> 4;
    const int ln   = lane & 15;
    const bool is_compute = (wv < 4);
    const int tid2 = tid & 255;          // index within service half (wv>=4)

    // ---------------- setup ----------------
    for (int i = tid; i < 2 * BT * HSTR; i += NT) ((unsigned short*)hbuf)[i] = 0;
    if (tid < BT) {
        if (tid < BTL) {
            float s = scale[b0 + tid];
            scl_s[tid] = s;
            inv_s[tid] = 1.0f / fmaxf(s, 1e-4f);
            sx[tid * 68 + 64] = log1pf(s);
        } else {
            scl_s[tid] = 1.0f;          // dead rows: finite, never stored
            inv_s[tid] = 0.0f;
            sx[tid * 68 + 64] = 0.0f;
        }
    }
    if (tid < BT * 4) {
        int r = tid >> 2, e = tid & 3;
        if (r < BTL) {
            int c = cats[(b0 + r) * 4 + e];
            const float* eb = (e == 0 ? emb0 : e == 1 ? emb1 : e == 2 ? emb2 : emb3);
            for (int j = 0; j < 16; ++j) sx[r * 68 + e * 16 + j] = eb[c * 16 + j];
        } else {
            for (int j = 0; j < 16; ++j) sx[r * 68 + e * 16 + j] = 0.0f;
        }
    }
    __syncthreads();

    // sbias[r][n] = bias[n] + static_x[r] . w_ih[11..75][n]; n = tid&255, rows split by tid>>8
    {
        const int n = tid & 255, half = tid >> 8;
        float bj = bias[n];
        float acc[8];
        #pragma unroll
        for (int r = 0; r < 8; ++r) acc[r] = bj;
        for (int k = 0; k < 65; ++k) {
            float w = w_ih[(11 + k) * NG + n];
            #pragma unroll
            for (int r = 0; r < 8; ++r) acc[r] += sx[(half * 8 + r) * 68 + k] * w;
        }
        #pragma unroll
        for (int r = 0; r < 8; ++r) sbias[(half * 8 + r) * SBSTR + n] = acc[r];
    }
    __syncthreads();

    // ---------------- register-resident weights + sbias fragments (compute waves) ----------------
    // gate scale factors folded into weights/bias
    bf16x8 bfrag[4][3];
    f32x4  sbf[4];
    if (is_compute) {
        #pragma unroll
        for (int ti = 0; ti < 4; ++ti) {
            const float gsc = (ti == 2) ? (-2.0f * LOG2E) : (-LOG2E);
            const int n = ln + 16 * (wv + 4 * ti);   // gate ti, unit 16wv+ln
            #pragma unroll
            for (int c = 0; c < 3; ++c) {
                #pragma unroll
                for (int j = 0; j < 8; ++j) {
                    int k = qd * 8 + 32 * c + j;
                    float w;
                    if (k < 64)                  w = w_hh[k * NG + n];
                    else if (k == 64 || k == 75) w = w_ih[n];
                    else if (k <= 74)            w = w_ih[(k - 64) * NG + n];
                    else                         w = 0.0f;
                    bfrag[ti][c][j] = (bf16_t)(w * gsc);
                }
            }
            #pragma unroll
            for (int r = 0; r < 4; ++r)
                sbf[ti][r] = sbias[(qd * 4 + r) * SBSTR + n] * gsc;
        }
    }

    // head fragments (used by wave 4): B = w_out padded to 16 cols, C = b_out
    bf16x8 wob0, wob1;
    f32x4  bC;
    float  scl4[4];
    #pragma unroll
    for (int j = 0; j < 8; ++j) {
        wob0[j] = (bf16_t)((ln < 2) ? w_out[(qd * 8 + j) * 2 + ln] : 0.0f);
        wob1[j] = (bf16_t)((ln < 2) ? w_out[(32 + qd * 8 + j) * 2 + ln] : 0.0f);
    }
    #pragma unroll
    for (int r = 0; r < 4; ++r) {
        bC[r]   = (ln < 2) ? b_out[ln] : 0.0f;
        scl4[r] = (ln == 0) ? scl_s[qd * 4 + r] : 1.0f;   // mus scaled, alphas not
    }

    __syncthreads();   // all sbias/sx reads done -> safe to overwrite with pcx

    // zero pcx (both buffers; establishes permanent-zero slots 12..15 AND rows 8..15)
    for (int i = tid; i < (2 * CH * BT * PSTR) / 2; i += NT) ((int*)smemA)[i] = 0;
    __syncthreads();

    // fill pcx chunk 0 (steps 0..31) — live rows only
    if (tid < 256) {
        const int row = tid >> 4, i5 = tid & 15;
        if (row < BTL) {
            const float* cr = cov + (size_t)(b0 + row) * (SS * 10);
            #pragma unroll
            for (int j = 0; j < 20; ++j) {
                int e = i5 + 16 * j, tp = e / 10, k = e - 10 * tp;
                pcx[((0 * CH + tp) * BT + row) * PSTR + 1 + k] = f2bf(cr[e]);
            }
            float pv0 = (i5 == 0) ? 0.0f : target[(size_t)(b0 + row) * SS + i5 - 1] * inv_s[row];
            float pv1 = target[(size_t)(b0 + row) * SS + i5 + 15] * inv_s[row];
            unsigned short m0 = f2bf(pv0), m1 = f2bf(pv1);
            pcx[((0 * CH + i5) * BT + row) * PSTR + 0]       = m0;
            pcx[((0 * CH + i5) * BT + row) * PSTR + 11]      = f2bf(pv0 - bf2f(m0));
            pcx[((0 * CH + i5 + 16) * BT + row) * PSTR + 0]  = m1;
            pcx[((0 * CH + i5 + 16) * BT + row) * PSTR + 11] = f2bf(pv1 - bf2f(m1));
        }
    }
    __syncthreads();

    // prime a2(0) and acc_pre(0) = x-part of gates for t=0 (compute waves)
    bf16x8 a2 = {};
    f32x4 acc_pre[4];
    if (is_compute) {
        if (qd < 2)
            a2 = *(const bf16x8*)&pcx[((0 * CH + 0) * BT + ln) * PSTR + qd * 8];
        #pragma unroll
        for (int ti = 0; ti < 4; ++ti)
            acc_pre[ti] = __builtin_amdgcn_mfma_f32_16x16x32_bf16(a2, bfrag[ti][2], sbf[ti], 0, 0, 0);
    }

    float cst[4] = {0.0f, 0.0f, 0.0f, 0.0f};
    float crg[20];
    #pragma unroll
    for (int j = 0; j < 20; ++j) crg[j] = 0.0f;
    float trg0 = 0.0f, trg1 = 0.0f;

    // ---------------- time loop (ONE barrier per step) ----------------
    for (int t = 0; t < SS; ++t) {
        const int cur = t & 1, nxt = cur ^ 1;
        __syncthreads();   // hbuf[cur] complete; acc_pre already holds x-part of gates(t)

        if (is_compute) {
            // ---- recurrence waves: 2-deep MFMA chain + lane-local cell ----
            const unsigned short* hb = &hbuf[cur][ln][0];
            bf16x8 a0 = *(const bf16x8*)(hb + qd * 8);
            bf16x8 a1 = *(const bf16x8*)(hb + 32 + qd * 8);

            f32x4 acc0 = __builtin_amdgcn_mfma_f32_16x16x32_bf16(a0, bfrag[0][0], acc_pre[0], 0, 0, 0);
            f32x4 acc1 = __builtin_amdgcn_mfma_f32_16x16x32_bf16(a0, bfrag[1][0], acc_pre[1], 0, 0, 0);
            f32x4 acc2 = __builtin_amdgcn_mfma_f32_16x16x32_bf16(a0, bfrag[2][0], acc_pre[2], 0, 0, 0);
            f32x4 acc3 = __builtin_amdgcn_mfma_f32_16x16x32_bf16(a0, bfrag[3][0], acc_pre[3], 0, 0, 0);
            acc0 = __builtin_amdgcn_mfma_f32_16x16x32_bf16(a1, bfrag[0][1], acc0, 0, 0, 0);
            acc1 = __builtin_amdgcn_mfma_f32_16x16x32_bf16(a1, bfrag[1][1], acc1, 0, 0, 0);
            acc2 = __builtin_amdgcn_mfma_f32_16x16x32_bf16(a1, bfrag[2][1], acc2, 0, 0, 0);
            acc3 = __builtin_amdgcn_mfma_f32_16x16x32_bf16(a1, bfrag[3][1], acc3, 0, 0, 0);

            // prefetch a2 for t+1 (pcx stable; committed >=15 steps earlier)
            if (t + 1 < SS && qd < 2)
                a2 = *(const bf16x8*)&pcx[((((t + 1) >> 5) & 1) * CH + ((t + 1) & 31)) * BT * PSTR
                                          + ln * PSTR + qd * 8];

            // lane-local LSTM cell: unit u = 16wv+ln, rows qd*4+r
            // acc0/1/3 = -log2e * (i,f,o preact); acc2 = -2log2e * g preact
            const int u = 16 * wv + ln;
            #pragma unroll
            for (int r = 0; r < 4; ++r) {
                float si = frcp_(1.0f + fexp2_(acc0[r]));
                float sf = frcp_(1.0f + fexp2_(acc1[r]));
                float tg = 2.0f * frcp_(1.0f + fexp2_(acc2[r])) - 1.0f;
                float so = frcp_(1.0f + fexp2_(acc3[r]));
                float cc = sf * cst[r] + si * tg;
                cst[r] = cc;
                float th = 2.0f * frcp_(1.0f + fexp2_((-2.0f * LOG2E) * cc)) - 1.0f;
                *(bf16_t*)&hbuf[nxt][qd * 4 + r][u] = (bf16_t)(so * th);
            }

            // x-part of gates for t+1 (independent of h; executes under the barrier wait)
            if (t + 1 < SS) {
                #pragma unroll
                for (int ti = 0; ti < 4; ++ti)
                    acc_pre[ti] = __builtin_amdgcn_mfma_f32_16x16x32_bf16(a2, bfrag[ti][2], sbf[ti], 0, 0, 0);
            }
        } else {
            // ---- service waves ----
            if ((t & 31) == 0 && t < 480) {
                const int row = tid2 >> 4, i5 = tid2 & 15, t0n = t + CH;
                if (row < BTL) {
                    const float* cr = cov + (size_t)(b0 + row) * (SS * 10) + t0n * 10;
                    #pragma unroll
                    for (int j = 0; j < 20; ++j) crg[j] = cr[i5 + 16 * j];
                    const float* tr = target + (size_t)(b0 + row) * SS + t0n + i5;
                    trg0 = tr[-1];
                    trg1 = tr[15];
                }
            }

            // head for t-1 via MFMA on wave 4 (reads h_{t-1} fragments; no shfl chain)
            if (wv == 4 && t > 0) {
                const unsigned short* hb = &hbuf[cur][ln][0];
                bf16x8 a0 = *(const bf16x8*)(hb + qd * 8);
                bf16x8 a1 = *(const bf16x8*)(hb + 32 + qd * 8);
                f32x4 hacc = __builtin_amdgcn_mfma_f32_16x16x32_bf16(a0, wob0, bC, 0, 0, 0);
                hacc = __builtin_amdgcn_mfma_f32_16x16x32_bf16(a1, wob1, hacc, 0, 0, 0);
                if (ln < 2) {
                    #pragma unroll
                    for (int r = 0; r < 4; ++r) {
                        float sp = softplus_(hacc[r]) + 1e-4f;
                        obuf[((t - 1) >> 5) & 1][(t - 1) & 31][ln * 16 + qd * 4 + r] = sp * scl4[r];
                    }
                }
            }

            if ((t & 31) == 16) {
                const int c = t >> 5;
                if (c < 15) {
                    const int row = tid2 >> 4, i5 = tid2 & 15, nb = (c + 1) & 1;
                    if (row < BTL) {
                        float pv0 = trg0 * inv_s[row];
                        float pv1 = trg1 * inv_s[row];
                        unsigned short m0 = f2bf(pv0), m1 = f2bf(pv1);
                        pcx[((nb * CH + i5) * BT + row) * PSTR + 0]       = m0;
                        pcx[((nb * CH + i5) * BT + row) * PSTR + 11]      = f2bf(pv0 - bf2f(m0));
                        pcx[((nb * CH + i5 + 16) * BT + row) * PSTR + 0]  = m1;
                        pcx[((nb * CH + i5 + 16) * BT + row) * PSTR + 11] = f2bf(pv1 - bf2f(m1));
                        #pragma unroll
                        for (int j = 0; j < 20; ++j) {
                            int e = i5 + 16 * j, tp = e / 10, k = e - 10 * tp;
                            pcx[((nb * CH + tp) * BT + row) * PSTR + 1 + k] = f2bf(crg[j]);
                        }
                    }
                }
                if (c >= 1) {
                    const int pb = (c - 1) & 1, t0p = (c - 1) << 5;
                    #pragma unroll
                    for (int h = 0; h < 4; ++h) {
                        int e = tid2 + 256 * h;
                        int tte = e & 31, rowe = (e >> 5) & 15, pe = e >> 9;
                        if (rowe < BTL)
                            out[(pe ? (BB * SS) : 0) + (size_t)(b0 + rowe) * SS + t0p + tte] =
                                obuf[pb][tte][pe * 16 + rowe];
                    }
                }
            }
        }
    }

    // ---------------- epilogue: head for t=511 (h in hbuf[0]) + flush chunk 15 ----------------
    __syncthreads();
    if (wv == 4) {
        const unsigned short* hb = &hbuf[0][ln][0];
        bf16x8 a0 = *(const bf16x8*)(hb + qd * 8);
        bf16x8 a1 = *(const bf16x8*)(hb + 32 + qd * 8);
        f32x4 hacc = __builtin_amdgcn_mfma_f32_16x16x32_bf16(a0, wob0, bC, 0, 0, 0);
        hacc = __builtin_amdgcn_mfma_f32_16x16x32_bf16(a1, wob1, hacc, 0, 0, 0);
        if (ln < 2) {
            #pragma unroll
            for (int r = 0; r < 4; ++r) {
                float sp = softplus_(hacc[r]) + 1e-4f;
                obuf[1][31][ln * 16 + qd * 4 + r] = sp * scl4[r];
            }
        }
    }
    __syncthreads();
    #pragma unroll
    for (int h = 0; h < 2; ++h) {
        int e = tid + NT * h;
        int tte = e & 31, rowe = (e >> 5) & 15, pe = e >> 9;
        if (rowe < BTL)
            out[(pe ? (BB * SS) : 0) + (size_t)(b0 + rowe) * SS + 480 + tte] =
                obuf[1][tte][pe * 16 + rowe];
    }
}

extern "C" void kernel_launch(void* const* d_in, const int* in_sizes, int n_in,
                              void* d_out, int out_size, void* d_ws, size_t ws_size,
                              hipStream_t stream) {
    deepar_kernel<<<BB / BTL, NT, 0, stream>>>(
        (const float*)d_in[0], (const float*)d_in[1], (const int*)d_in[2],
        (const float*)d_in[3], (const float*)d_in[4], (const float*)d_in[5],
        (const float*)d_in[6], (const float*)d_in[7], (const float*)d_in[8],
        (const float*)d_in[9], (const float*)d_in[10], (const float*)d_in[11],
        (const float*)d_in[12], (float*)d_out);
}

// Round 3
// 721.369 us; speedup vs baseline: 1.1777x; 1.1777x over previous
//
#include <hip/hip_runtime.h>

#define BB 4096
#define SS 512
#define NG 256     // 4*HID gate columns
#define BTL 8      // live batch rows per workgroup (grid = 512; target 2-3 blocks/CU)
#define NT 256     // 4 waves, all compute; service duties cooperative/rotating
#define CH 32      // time-chunk length
#define HSTR 68    // hbuf row stride (shorts)
#define PSTR 16    // pcx row stride (shorts): slots 0..11 real, 12..15 zero
#define SBSTR 264  // sbias row stride (floats), overlaid on pcx
#define OSTR 17    // obuf row stride (floats): 16 data + 1 pad

typedef __bf16 bf16_t;
typedef bf16_t bf16x8 __attribute__((ext_vector_type(8)));
typedef float  f32x4  __attribute__((ext_vector_type(4)));

__device__ __forceinline__ unsigned short f2bf(float x) {
    union { float f; unsigned u; } q{x};
    unsigned r = (q.u + 0x7fffu + ((q.u >> 16) & 1u)) >> 16;
    return (unsigned short)r;
}
__device__ __forceinline__ float bf2f(unsigned short s) {
    union { unsigned u; float f; } q{((unsigned)s) << 16};
    return q.f;
}
#define LOG2E 1.4426950408889634f
__device__ __forceinline__ float frcp_(float x)  { return __builtin_amdgcn_rcpf(x); }
__device__ __forceinline__ float fexp2_(float x) { return __builtin_amdgcn_exp2f(x); }
__device__ __forceinline__ float flog2_(float x) { return __builtin_amdgcn_logf(x); }
__device__ __forceinline__ float softplus_(float x){ return x > 20.0f ? x : 0.6931471805599453f * flog2_(1.0f + fexp2_(LOG2E * x)); }

// K-slot layout (96): 0..63 = h, 64 = prev, 65..74 = cov, 75 = prev residual, 76..95 = 0.
// Gate columns pre-scaled: i,f,o by -log2e; g by -2log2e:
//   sigma(x) = rcp(1+exp2(y)),  tanh(x) = 2*rcp(1+exp2(z)) - 1.
// 8 live rows/block; A-matrix rows 8..15 read a zero block (zb). After the gate
// MFMAs, __shfl_xor(.,32) moves rows {2,3}/{6,7} into qd>=2 lanes so every lane
// runs 2 cells (trans 320->160 cyc/wave). Head (2 MFMAs, reuses a0/a1) rotates
// wv==t&3. Staging/flush cooperative over all 256 threads. One barrier/step.
// 2-3 blocks/CU at independent barrier phases supply the latency hiding.
__global__ __launch_bounds__(NT, 3)
void deepar_kernel(const float* __restrict__ target, const float* __restrict__ cov,
                   const int* __restrict__ cats, const float* __restrict__ scale,
                   const float* __restrict__ emb0, const float* __restrict__ emb1,
                   const float* __restrict__ emb2, const float* __restrict__ emb3,
                   const float* __restrict__ w_ih, const float* __restrict__ w_hh,
                   const float* __restrict__ bias, const float* __restrict__ w_out,
                   const float* __restrict__ b_out, float* __restrict__ out)
{
    // pcx (2*32*8*16 shorts = 16384 B) overlays sbias(8448 B)+sx(2176 B) scratch
    __shared__ __attribute__((aligned(16))) unsigned char smemA[2 * CH * BTL * PSTR * 2];
    __shared__ __attribute__((aligned(16))) unsigned short hbuf[2][BTL][HSTR]; // 2176 B
    __shared__ float obuf[2][CH][OSTR];                                        // 4352 B
    __shared__ __attribute__((aligned(16))) unsigned short zb[64];             //  128 B
    __shared__ float inv_s[BTL], scl_s[BTL];

    unsigned short* pcx   = (unsigned short*)smemA;
    float*          sbias = (float*)smemA;
    float*          sx    = (float*)(smemA + BTL * SBSTR * 4);

    const int tid  = threadIdx.x;
    const int b0   = blockIdx.x * BTL;
    const int lane = tid & 63;
    const int wv   = tid >> 6;
    const int qd   = lane >> 4;
    const int ln   = lane & 15;

    // ---------------- setup ----------------
    for (int i = tid; i < 2 * BTL * HSTR; i += NT) ((unsigned short*)hbuf)[i] = 0;
    if (tid < 64) zb[tid] = 0;
    if (tid < BTL) {
        float s = scale[b0 + tid];
        scl_s[tid] = s;
        inv_s[tid] = 1.0f / fmaxf(s, 1e-4f);
        sx[tid * 68 + 64] = log1pf(s);
    }
    if (tid < BTL * 4) {
        int r = tid >> 2, e = tid & 3;
        int c = cats[(b0 + r) * 4 + e];
        const float* eb = (e == 0 ? emb0 : e == 1 ? emb1 : e == 2 ? emb2 : emb3);
        for (int j = 0; j < 16; ++j) sx[r * 68 + e * 16 + j] = eb[c * 16 + j];
    }
    __syncthreads();

    // sbias[r][n] = bias[n] + static_x[r] . w_ih[11..75][n]; n = tid, rows 0..7
    {
        const int n = tid;
        float bj = bias[n];
        float acc[BTL];
        #pragma unroll
        for (int r = 0; r < BTL; ++r) acc[r] = bj;
        for (int k = 0; k < 65; ++k) {
            float w = w_ih[(11 + k) * NG + n];
            #pragma unroll
            for (int r = 0; r < BTL; ++r) acc[r] += sx[r * 68 + k] * w;
        }
        #pragma unroll
        for (int r = 0; r < BTL; ++r) sbias[r * SBSTR + n] = acc[r];
    }
    __syncthreads();

    // ---------------- register-resident weights + sbias fragments (all waves) ----------------
    bf16x8 bfrag[4][3];
    f32x4  sbf[4];
    {
        #pragma unroll
        for (int ti = 0; ti < 4; ++ti) {
            const float gsc = (ti == 2) ? (-2.0f * LOG2E) : (-LOG2E);
            const int n = ln + 16 * (wv + 4 * ti);   // gate ti, unit 16wv+ln
            #pragma unroll
            for (int c = 0; c < 3; ++c) {
                #pragma unroll
                for (int j = 0; j < 8; ++j) {
                    int k = qd * 8 + 32 * c + j;
                    float w;
                    if (k < 64)                  w = w_hh[k * NG + n];
                    else if (k == 64 || k == 75) w = w_ih[n];
                    else if (k <= 74)            w = w_ih[(k - 64) * NG + n];
                    else                         w = 0.0f;
                    bfrag[ti][c][j] = (bf16_t)(w * gsc);
                }
            }
            #pragma unroll
            for (int r = 0; r < 4; ++r)
                sbf[ti][r] = sbias[((qd * 4 + r) & 7) * SBSTR + n] * gsc;  // &7: dead rows alias live (discarded)
        }
    }

    // head fragments (all waves; duty rotates): B = w_out padded to 16 cols, C = b_out
    bf16x8 wob0, wob1;
    f32x4  bC;
    float  scl4[4];
    #pragma unroll
    for (int j = 0; j < 8; ++j) {
        wob0[j] = (bf16_t)((ln < 2) ? w_out[(qd * 8 + j) * 2 + ln] : 0.0f);
        wob1[j] = (bf16_t)((ln < 2) ? w_out[(32 + qd * 8 + j) * 2 + ln] : 0.0f);
    }
    #pragma unroll
    for (int r = 0; r < 4; ++r) {
        bC[r]   = (ln < 2) ? b_out[ln] : 0.0f;
        scl4[r] = (ln == 0) ? scl_s[(qd * 4 + r) & 7] : 1.0f;   // mus scaled, alphas not
    }

    __syncthreads();   // all sbias/sx reads done -> safe to overwrite with pcx

    // zero pcx (both buffers; establishes permanent-zero slots 12..15)
    for (int i = tid; i < (2 * CH * BTL * PSTR) / 2; i += NT) ((int*)smemA)[i] = 0;
    __syncthreads();

    // fill pcx chunk 0 (steps 0..31): 32 threads per row, one step each
    {
        const int row = tid >> 5, sl = tid & 31;
        const float* cr = cov + (size_t)(b0 + row) * (SS * 10);
        #pragma unroll
        for (int j = 0; j < 10; ++j) {
            int e = sl + 32 * j, tp = e / 10, k = e - 10 * tp;
            pcx[((0 * CH + tp) * BTL + row) * PSTR + 1 + k] = f2bf(cr[e]);
        }
        float pv = (sl == 0) ? 0.0f : target[(size_t)(b0 + row) * SS + sl - 1] * inv_s[row];
        unsigned short m0 = f2bf(pv);
        pcx[((0 * CH + sl) * BTL + row) * PSTR + 0]  = m0;
        pcx[((0 * CH + sl) * BTL + row) * PSTR + 11] = f2bf(pv - bf2f(m0));
    }
    __syncthreads();

    // prime a2(0) and acc_pre(0) = x-part of gates for t=0
    bf16x8 a2 = {};
    f32x4 acc_pre[4];
    {
        if (qd < 2)
            a2 = *(const bf16x8*)((ln < BTL)
                    ? &pcx[((0 * CH + 0) * BTL + ln) * PSTR + qd * 8]
                    : &zb[qd * 8]);
        #pragma unroll
        for (int ti = 0; ti < 4; ++ti)
            acc_pre[ti] = __builtin_amdgcn_mfma_f32_16x16x32_bf16(a2, bfrag[ti][2], sbf[ti], 0, 0, 0);
    }

    float cst[2] = {0.0f, 0.0f};   // c-state for this lane's 2 rows
    float crg[10];
    #pragma unroll
    for (int j = 0; j < 10; ++j) crg[j] = 0.0f;
    float trgv = 0.0f;

    // ---------------- time loop (ONE barrier per step) ----------------
    for (int t = 0; t < SS; ++t) {
        const int cur = t & 1, nxt = cur ^ 1;
        __syncthreads();   // hbuf[cur] complete; acc_pre already holds x-part of gates(t)

        // ---- all 4 waves: 2-deep MFMA chain ----
        const unsigned short* hb = (ln < BTL) ? &hbuf[cur][ln][0] : &zb[0];
        bf16x8 a0 = *(const bf16x8*)(hb + qd * 8);
        bf16x8 a1 = *(const bf16x8*)(hb + 32 + qd * 8);

        f32x4 acc0 = __builtin_amdgcn_mfma_f32_16x16x32_bf16(a0, bfrag[0][0], acc_pre[0], 0, 0, 0);
        f32x4 acc1 = __builtin_amdgcn_mfma_f32_16x16x32_bf16(a0, bfrag[1][0], acc_pre[1], 0, 0, 0);
        f32x4 acc2 = __builtin_amdgcn_mfma_f32_16x16x32_bf16(a0, bfrag[2][0], acc_pre[2], 0, 0, 0);
        f32x4 acc3 = __builtin_amdgcn_mfma_f32_16x16x32_bf16(a0, bfrag[3][0], acc_pre[3], 0, 0, 0);
        acc0 = __builtin_amdgcn_mfma_f32_16x16x32_bf16(a1, bfrag[0][1], acc0, 0, 0, 0);
        acc1 = __builtin_amdgcn_mfma_f32_16x16x32_bf16(a1, bfrag[1][1], acc1, 0, 0, 0);
        acc2 = __builtin_amdgcn_mfma_f32_16x16x32_bf16(a1, bfrag[2][1], acc2, 0, 0, 0);
        acc3 = __builtin_amdgcn_mfma_f32_16x16x32_bf16(a1, bfrag[3][1], acc3, 0, 0, 0);

        // prefetch a2 for t+1 (pcx stable; committed >=15 steps earlier)
        if (t + 1 < SS && qd < 2)
            a2 = *(const bf16x8*)((ln < BTL)
                    ? &pcx[((((t + 1) >> 5) & 1) * CH + ((t + 1) & 31)) * BTL * PSTR
                           + ln * PSTR + qd * 8]
                    : &zb[qd * 8]);

        // ---- redistribute live rows to all lanes: qd>=2 takes rows {2,3}/{6,7} ----
        float xi0 = __shfl_xor(acc0[2], 32), xi1 = __shfl_xor(acc0[3], 32);
        float xf0 = __shfl_xor(acc1[2], 32), xf1 = __shfl_xor(acc1[3], 32);
        float xg0 = __shfl_xor(acc2[2], 32), xg1 = __shfl_xor(acc2[3], 32);
        float xo0 = __shfl_xor(acc3[2], 32), xo1 = __shfl_xor(acc3[3], 32);
        const bool hi = (qd >= 2);
        float gi[2] = { hi ? xi0 : acc0[0], hi ? xi1 : acc0[1] };
        float gf[2] = { hi ? xf0 : acc1[0], hi ? xf1 : acc1[1] };
        float gg[2] = { hi ? xg0 : acc2[0], hi ? xg1 : acc2[1] };
        float go[2] = { hi ? xo0 : acc3[0], hi ? xo1 : acc3[1] };

        // lane-local LSTM cell: 2 rows/lane; row = (qd&1)*4 + (qd>>1)*2 + rr
        const int rowb = (qd & 1) * 4 + (qd >> 1) * 2;
        const int u = 16 * wv + ln;
        #pragma unroll
        for (int rr = 0; rr < 2; ++rr) {
            float si = frcp_(1.0f + fexp2_(gi[rr]));
            float sf = frcp_(1.0f + fexp2_(gf[rr]));
            float tg = 2.0f * frcp_(1.0f + fexp2_(gg[rr])) - 1.0f;
            float so = frcp_(1.0f + fexp2_(go[rr]));
            float cc = sf * cst[rr] + si * tg;
            cst[rr] = cc;
            float th = 2.0f * frcp_(1.0f + fexp2_((-2.0f * LOG2E) * cc)) - 1.0f;
            *(bf16_t*)&hbuf[nxt][rowb + rr][u] = (bf16_t)(so * th);
        }

        // ---- head for t-1 (rotating wave; reuses this wave's a0/a1) ----
        if (t > 0 && wv == (t & 3)) {
            f32x4 hacc = __builtin_amdgcn_mfma_f32_16x16x32_bf16(a0, wob0, bC, 0, 0, 0);
            hacc = __builtin_amdgcn_mfma_f32_16x16x32_bf16(a1, wob1, hacc, 0, 0, 0);
            if (ln < 2 && qd < 2) {
                #pragma unroll
                for (int r = 0; r < 4; ++r) {
                    float sp = softplus_(hacc[r]) + 1e-4f;
                    obuf[((t - 1) >> 5) & 1][(t - 1) & 31][(qd * 4 + r) * 2 + ln] = sp * scl4[r];
                }
            }
        }

        // x-part of gates for t+1 (independent of h)
        if (t + 1 < SS) {
            #pragma unroll
            for (int ti = 0; ti < 4; ++ti)
                acc_pre[ti] = __builtin_amdgcn_mfma_f32_16x16x32_bf16(a2, bfrag[ti][2], sbf[ti], 0, 0, 0);
        }

        // ---- cooperative staging / flush (all 256 threads) ----
        if ((t & 31) == 0 && t < 480) {   // issue loads for chunk (t>>5)+1
            const int row = tid >> 5, sl = tid & 31, t0n = t + CH;
            const float* cr = cov + (size_t)(b0 + row) * (SS * 10) + t0n * 10;
            #pragma unroll
            for (int j = 0; j < 10; ++j) crg[j] = cr[sl + 32 * j];
            trgv = target[(size_t)(b0 + row) * SS + t0n + sl - 1];
        }

        if ((t & 31) == 16) {
            const int c = t >> 5;
            if (c < 15) {                 // commit chunk c+1
                const int row = tid >> 5, sl = tid & 31, nb = (c + 1) & 1;
                float pv = trgv * inv_s[row];
                unsigned short m0 = f2bf(pv);
                pcx[((nb * CH + sl) * BTL + row) * PSTR + 0]  = m0;
                pcx[((nb * CH + sl) * BTL + row) * PSTR + 11] = f2bf(pv - bf2f(m0));
                #pragma unroll
                for (int j = 0; j < 10; ++j) {
                    int e = sl + 32 * j, tp = e / 10, k = e - 10 * tp;
                    pcx[((nb * CH + tp) * BTL + row) * PSTR + 1 + k] = f2bf(crg[j]);
                }
            }
            if (c >= 1) {                 // flush obuf chunk c-1
                const int pb = (c - 1) & 1, t0p = (c - 1) << 5;
                #pragma unroll
                for (int h = 0; h < 2; ++h) {
                    int e = tid + NT * h;
                    int tte = e & 31, rowe = (e >> 5) & 7, pe = e >> 8;
                    out[(pe ? (BB * SS) : 0) + (size_t)(b0 + rowe) * SS + t0p + tte] =
                        obuf[pb][tte][rowe * 2 + pe];
                }
            }
        }
    }

    // ---------------- epilogue: head for t=511 (h in hbuf[0]) + flush chunk 15 ----------------
    __syncthreads();
    if (wv == 0) {
        const unsigned short* hb = (ln < BTL) ? &hbuf[0][ln][0] : &zb[0];
        bf16x8 a0 = *(const bf16x8*)(hb + qd * 8);
        bf16x8 a1 = *(const bf16x8*)(hb + 32 + qd * 8);
        f32x4 hacc = __builtin_amdgcn_mfma_f32_16x16x32_bf16(a0, wob0, bC, 0, 0, 0);
        hacc = __builtin_amdgcn_mfma_f32_16x16x32_bf16(a1, wob1, hacc, 0, 0, 0);
        if (ln < 2 && qd < 2) {
            #pragma unroll
            for (int r = 0; r < 4; ++r) {
                float sp = softplus_(hacc[r]) + 1e-4f;
                obuf[1][31][(qd * 4 + r) * 2 + ln] = sp * scl4[r];
            }
        }
    }
    __syncthreads();
    #pragma unroll
    for (int h = 0; h < 2; ++h) {
        int e = tid + NT * h;
        int tte = e & 31, rowe = (e >> 5) & 7, pe = e >> 8;
        out[(pe ? (BB * SS) : 0) + (size_t)(b0 + rowe) * SS + 480 + tte] =
            obuf[1][tte][rowe * 2 + pe];
    }
}

extern "C" void kernel_launch(void* const* d_in, const int* in_sizes, int n_in,
                              void* d_out, int out_size, void* d_ws, size_t ws_size,
                              hipStream_t stream) {
    deepar_kernel<<<BB / BTL, NT, 0, stream>>>(
        (const float*)d_in[0], (const float*)d_in[1], (const int*)d_in[2],
        (const float*)d_in[3], (const float*)d_in[4], (const float*)d_in[5],
        (const float*)d_in[6], (const float*)d_in[7], (const float*)d_in[8],
        (const float*)d_in[9], (const float*)d_in[10], (const float*)d_in[11],
        (const float*)d_in[12], (float*)d_out);
}

// Round 4
// 560.923 us; speedup vs baseline: 1.5145x; 1.2860x over previous
//
#include <hip/hip_runtime.h>

#define BB 4096
#define SS 512
#define NG 256     // 4*HID gate columns
#define BT 16      // batch rows per workgroup (grid = 256 = #CUs)
#define NT 256     // 4 waves, all compute; head rotates, staging folded in
#define CH 32      // time-chunk length
#define HSTR 68    // hbuf row stride (shorts)
#define PSTR 16    // pcx row stride (shorts): slots 0..11 real, 12..15 zero
#define SBSTR 264  // sbias row stride (floats), overlaid on pcx
#define OSTR 33    // obuf row stride (floats)

typedef __bf16 bf16_t;
typedef bf16_t bf16x8 __attribute__((ext_vector_type(8)));
typedef float  f32x4  __attribute__((ext_vector_type(4)));

__device__ __forceinline__ unsigned short f2bf(float x) {
    union { float f; unsigned u; } q{x};
    unsigned r = (q.u + 0x7fffu + ((q.u >> 16) & 1u)) >> 16;
    return (unsigned short)r;
}
__device__ __forceinline__ float bf2f(unsigned short s) {
    union { unsigned u; float f; } q{((unsigned)s) << 16};
    return q.f;
}
#define LOG2E 1.4426950408889634f
__device__ __forceinline__ float frcp_(float x)  { return __builtin_amdgcn_rcpf(x); }
__device__ __forceinline__ float fexp2_(float x) { return __builtin_amdgcn_exp2f(x); }
__device__ __forceinline__ float flog2_(float x) { return __builtin_amdgcn_logf(x); }
__device__ __forceinline__ float softplus_(float x){ return x > 20.0f ? x : 0.6931471805599453f * flog2_(1.0f + fexp2_(LOG2E * x)); }

// K-slot layout (96): 0..63 = h, 64 = prev, 65..74 = cov, 75 = prev residual, 76..95 = 0.
// Gate columns pre-scaled: i,f,o by -log2e; g by -2log2e. Fused-denominator cell
// (7 trans/cell instead of 10):
//   a=e^-i, fe=e^-f, b=e^-2g, oe=e^-o (each exp2 of prescaled acc, clamped at 30)
//   c' = (c*(1+a)(1+b) + (1-b)(1+fe)) * rcp((1+a)(1+b)(1+fe))
//   h  = (1-d) * rcp((1+oe)(1+d)),  d = exp2(-2log2e*c')
// 4 waves, wave wv owns all 4 gates for units 16wv..16wv+15; cell lane-local
// (4 rows/lane). Head for t-1 rotates wv==(t&3), reusing that wave's a0/a1.
// Staging (chunk loads/commits) and obuf flush fold in at 32-step cadence.
// acc_pre MFMAs sit in the post-barrier lgkm shadow of the a0/a1 ds_reads.
// One barrier per step.
__global__ __launch_bounds__(NT, 1)
void deepar_kernel(const float* __restrict__ target, const float* __restrict__ cov,
                   const int* __restrict__ cats, const float* __restrict__ scale,
                   const float* __restrict__ emb0, const float* __restrict__ emb1,
                   const float* __restrict__ emb2, const float* __restrict__ emb3,
                   const float* __restrict__ w_ih, const float* __restrict__ w_hh,
                   const float* __restrict__ bias, const float* __restrict__ w_out,
                   const float* __restrict__ b_out, float* __restrict__ out)
{
    // pcx (2*32*16*16 shorts = 32768 B) overlays sbias(16896 B)+sx(4352 B) scratch
    __shared__ __attribute__((aligned(16))) unsigned char smemA[2 * CH * BT * PSTR * 2];
    __shared__ __attribute__((aligned(16))) unsigned short hbuf[2][BT][HSTR]; //  4352 B
    __shared__ float obuf[2][CH][OSTR];                                       //  8448 B
    __shared__ float inv_s[BT], scl_s[BT];

    unsigned short* pcx   = (unsigned short*)smemA;
    float*          sbias = (float*)smemA;
    float*          sx    = (float*)(smemA + BT * SBSTR * 4);

    const int tid  = threadIdx.x;
    const int b0   = blockIdx.x * BT;
    const int lane = tid & 63;
    const int wv   = tid >> 6;
    const int qd   = lane >> 4;
    const int ln   = lane & 15;

    // ---------------- setup ----------------
    for (int i = tid; i < 2 * BT * HSTR; i += NT) ((unsigned short*)hbuf)[i] = 0;
    if (tid < BT) {
        float s = scale[b0 + tid];
        scl_s[tid] = s;
        inv_s[tid] = 1.0f / fmaxf(s, 1e-4f);
        sx[tid * 68 + 64] = log1pf(s);
    }
    if (tid < BT * 4) {
        int r = tid >> 2, e = tid & 3;
        int c = cats[(b0 + r) * 4 + e];
        const float* eb = (e == 0 ? emb0 : e == 1 ? emb1 : e == 2 ? emb2 : emb3);
        for (int j = 0; j < 16; ++j) sx[r * 68 + e * 16 + j] = eb[c * 16 + j];
    }
    __syncthreads();

    // sbias[r][n] = bias[n] + static_x[r] . w_ih[11..75][n]; n = tid, all 16 rows
    {
        const int n = tid;
        float bj = bias[n];
        float acc[BT];
        #pragma unroll
        for (int r = 0; r < BT; ++r) acc[r] = bj;
        for (int k = 0; k < 65; ++k) {
            float w = w_ih[(11 + k) * NG + n];
            #pragma unroll
            for (int r = 0; r < BT; ++r) acc[r] += sx[r * 68 + k] * w;
        }
        #pragma unroll
        for (int r = 0; r < BT; ++r) sbias[r * SBSTR + n] = acc[r];
    }
    __syncthreads();

    // ---------------- register-resident weights + sbias fragments (all waves) ----------------
    bf16x8 bfrag[4][3];
    f32x4  sbf[4];
    {
        #pragma unroll
        for (int ti = 0; ti < 4; ++ti) {
            const float gsc = (ti == 2) ? (-2.0f * LOG2E) : (-LOG2E);
            const int n = ln + 16 * (wv + 4 * ti);   // gate ti, unit 16wv+ln
            #pragma unroll
            for (int c = 0; c < 3; ++c) {
                #pragma unroll
                for (int j = 0; j < 8; ++j) {
                    int k = qd * 8 + 32 * c + j;
                    float w;
                    if (k < 64)                  w = w_hh[k * NG + n];
                    else if (k == 64 || k == 75) w = w_ih[n];
                    else if (k <= 74)            w = w_ih[(k - 64) * NG + n];
                    else                         w = 0.0f;
                    bfrag[ti][c][j] = (bf16_t)(w * gsc);
                }
            }
            #pragma unroll
            for (int r = 0; r < 4; ++r)
                sbf[ti][r] = sbias[(qd * 4 + r) * SBSTR + n] * gsc;
        }
    }

    // head fragments (all waves; duty rotates): B = w_out padded to 16 cols, C = b_out
    bf16x8 wob0, wob1;
    f32x4  bC;
    float  scl4[4];
    #pragma unroll
    for (int j = 0; j < 8; ++j) {
        wob0[j] = (bf16_t)((ln < 2) ? w_out[(qd * 8 + j) * 2 + ln] : 0.0f);
        wob1[j] = (bf16_t)((ln < 2) ? w_out[(32 + qd * 8 + j) * 2 + ln] : 0.0f);
    }
    #pragma unroll
    for (int r = 0; r < 4; ++r) {
        bC[r]   = (ln < 2) ? b_out[ln] : 0.0f;
        scl4[r] = (ln == 0) ? scl_s[qd * 4 + r] : 1.0f;   // mus scaled, alphas not
    }

    __syncthreads();   // all sbias/sx reads done -> safe to overwrite with pcx

    // zero pcx (both buffers; establishes the permanent-zero slots 12..15)
    for (int i = tid; i < (2 * CH * BT * PSTR) / 2; i += NT) ((int*)smemA)[i] = 0;
    __syncthreads();

    // fill pcx chunk 0 (steps 0..31)
    {
        const int row = tid >> 4, i5 = tid & 15;
        const float* cr = cov + (size_t)(b0 + row) * (SS * 10);
        #pragma unroll
        for (int j = 0; j < 20; ++j) {
            int e = i5 + 16 * j, tp = e / 10, k = e - 10 * tp;
            pcx[((0 * CH + tp) * BT + row) * PSTR + 1 + k] = f2bf(cr[e]);
        }
        float pv0 = (i5 == 0) ? 0.0f : target[(size_t)(b0 + row) * SS + i5 - 1] * inv_s[row];
        float pv1 = target[(size_t)(b0 + row) * SS + i5 + 15] * inv_s[row];
        unsigned short m0 = f2bf(pv0), m1 = f2bf(pv1);
        pcx[((0 * CH + i5) * BT + row) * PSTR + 0]       = m0;
        pcx[((0 * CH + i5) * BT + row) * PSTR + 11]      = f2bf(pv0 - bf2f(m0));
        pcx[((0 * CH + i5 + 16) * BT + row) * PSTR + 0]  = m1;
        pcx[((0 * CH + i5 + 16) * BT + row) * PSTR + 11] = f2bf(pv1 - bf2f(m1));
    }
    __syncthreads();

    // prime a2 = x(0) fragment
    bf16x8 a2 = {};
    if (qd < 2)
        a2 = *(const bf16x8*)&pcx[((0 * CH + 0) * BT + ln) * PSTR + qd * 8];

    float cst[4] = {0.0f, 0.0f, 0.0f, 0.0f};
    float crg[20];
    #pragma unroll
    for (int j = 0; j < 20; ++j) crg[j] = 0.0f;
    float trg0 = 0.0f, trg1 = 0.0f;

    // ---------------- time loop (ONE barrier per step) ----------------
    for (int t = 0; t < SS; ++t) {
        const int cur = t & 1, nxt = cur ^ 1;
        __syncthreads();   // hbuf[cur] complete; a2 holds x(t) fragment

        // ---- issue h reads; acc_pre MFMAs fill the lgkm shadow ----
        const unsigned short* hb = &hbuf[cur][ln][0];
        bf16x8 a0 = *(const bf16x8*)(hb + qd * 8);
        bf16x8 a1 = *(const bf16x8*)(hb + 32 + qd * 8);

        f32x4 acc0 = __builtin_amdgcn_mfma_f32_16x16x32_bf16(a2, bfrag[0][2], sbf[0], 0, 0, 0);
        f32x4 acc1 = __builtin_amdgcn_mfma_f32_16x16x32_bf16(a2, bfrag[1][2], sbf[1], 0, 0, 0);
        f32x4 acc2 = __builtin_amdgcn_mfma_f32_16x16x32_bf16(a2, bfrag[2][2], sbf[2], 0, 0, 0);
        f32x4 acc3 = __builtin_amdgcn_mfma_f32_16x16x32_bf16(a2, bfrag[3][2], sbf[3], 0, 0, 0);

        acc0 = __builtin_amdgcn_mfma_f32_16x16x32_bf16(a0, bfrag[0][0], acc0, 0, 0, 0);
        acc1 = __builtin_amdgcn_mfma_f32_16x16x32_bf16(a0, bfrag[1][0], acc1, 0, 0, 0);
        acc2 = __builtin_amdgcn_mfma_f32_16x16x32_bf16(a0, bfrag[2][0], acc2, 0, 0, 0);
        acc3 = __builtin_amdgcn_mfma_f32_16x16x32_bf16(a0, bfrag[3][0], acc3, 0, 0, 0);
        acc0 = __builtin_amdgcn_mfma_f32_16x16x32_bf16(a1, bfrag[0][1], acc0, 0, 0, 0);
        acc1 = __builtin_amdgcn_mfma_f32_16x16x32_bf16(a1, bfrag[1][1], acc1, 0, 0, 0);
        acc2 = __builtin_amdgcn_mfma_f32_16x16x32_bf16(a1, bfrag[2][1], acc2, 0, 0, 0);
        acc3 = __builtin_amdgcn_mfma_f32_16x16x32_bf16(a1, bfrag[3][1], acc3, 0, 0, 0);

        // prefetch a2 for t+1 (pcx stable; committed >=15 steps earlier)
        if (t + 1 < SS && qd < 2)
            a2 = *(const bf16x8*)&pcx[((((t + 1) >> 5) & 1) * CH + ((t + 1) & 31)) * BT * PSTR
                                      + ln * PSTR + qd * 8];

        // ---- fused-denominator LSTM cell: unit u = 16wv+ln, rows qd*4+r ----
        // acc0/1/3 = -log2e * (i,f,o preact); acc2 = -2log2e * g preact
        const int u = 16 * wv + ln;
        #pragma unroll
        for (int r = 0; r < 4; ++r) {
            float a  = fexp2_(fminf(acc0[r], 30.0f));   // e^-i
            float fe = fexp2_(fminf(acc1[r], 30.0f));   // e^-f
            float bb = fexp2_(fminf(acc2[r], 30.0f));   // e^-2g
            float oe = fexp2_(fminf(acc3[r], 30.0f));   // e^-o
            float p  = (1.0f + a) * (1.0f + bb);
            float q  = 1.0f + fe;
            float cc = (cst[r] * p + (1.0f - bb) * q) * frcp_(p * q);
            cst[r] = cc;
            float d  = fexp2_(fminf((-2.0f * LOG2E) * cc, 30.0f));
            float hv = (1.0f - d) * frcp_((1.0f + oe) * (1.0f + d));
            *(bf16_t*)&hbuf[nxt][qd * 4 + r][u] = (bf16_t)hv;
        }

        // ---- head for t-1 (rotating wave; reuses this wave's a0/a1) ----
        if (t > 0 && wv == (t & 3)) {
            f32x4 hacc = __builtin_amdgcn_mfma_f32_16x16x32_bf16(a0, wob0, bC, 0, 0, 0);
            hacc = __builtin_amdgcn_mfma_f32_16x16x32_bf16(a1, wob1, hacc, 0, 0, 0);
            if (ln < 2) {
                #pragma unroll
                for (int r = 0; r < 4; ++r) {
                    float sp = softplus_(hacc[r]) + 1e-4f;
                    obuf[((t - 1) >> 5) & 1][(t - 1) & 31][ln * 16 + qd * 4 + r] = sp * scl4[r];
                }
            }
        }

        // ---- staging / flush (all threads; 32-step cadence) ----
        if ((t & 31) == 0 && t < 480) {   // issue loads for chunk (t>>5)+1
            const int row = tid >> 4, i5 = tid & 15, t0n = t + CH;
            const float* cr = cov + (size_t)(b0 + row) * (SS * 10) + t0n * 10;
            #pragma unroll
            for (int j = 0; j < 20; ++j) crg[j] = cr[i5 + 16 * j];
            const float* tr = target + (size_t)(b0 + row) * SS + t0n + i5;
            trg0 = tr[-1];
            trg1 = tr[15];
        }

        if ((t & 31) == 16) {
            const int c = t >> 5;
            if (c < 15) {                 // commit chunk c+1
                const int row = tid >> 4, i5 = tid & 15, nb = (c + 1) & 1;
                float pv0 = trg0 * inv_s[row];
                float pv1 = trg1 * inv_s[row];
                unsigned short m0 = f2bf(pv0), m1 = f2bf(pv1);
                pcx[((nb * CH + i5) * BT + row) * PSTR + 0]       = m0;
                pcx[((nb * CH + i5) * BT + row) * PSTR + 11]      = f2bf(pv0 - bf2f(m0));
                pcx[((nb * CH + i5 + 16) * BT + row) * PSTR + 0]  = m1;
                pcx[((nb * CH + i5 + 16) * BT + row) * PSTR + 11] = f2bf(pv1 - bf2f(m1));
                #pragma unroll
                for (int j = 0; j < 20; ++j) {
                    int e = i5 + 16 * j, tp = e / 10, k = e - 10 * tp;
                    pcx[((nb * CH + tp) * BT + row) * PSTR + 1 + k] = f2bf(crg[j]);
                }
            }
            if (c >= 1) {                 // flush obuf chunk c-1
                const int pb = (c - 1) & 1, t0p = (c - 1) << 5;
                #pragma unroll
                for (int h = 0; h < 4; ++h) {
                    int e = tid + NT * h;
                    int tte = e & 31, rowe = (e >> 5) & 15, pe = e >> 9;
                    out[(pe ? (BB * SS) : 0) + (size_t)(b0 + rowe) * SS + t0p + tte] =
                        obuf[pb][tte][pe * 16 + rowe];
                }
            }
        }
    }

    // ---------------- epilogue: head for t=511 (h in hbuf[0]) + flush chunk 15 ----------------
    __syncthreads();
    if (wv == 0) {
        const unsigned short* hb = &hbuf[0][ln][0];
        bf16x8 a0 = *(const bf16x8*)(hb + qd * 8);
        bf16x8 a1 = *(const bf16x8*)(hb + 32 + qd * 8);
        f32x4 hacc = __builtin_amdgcn_mfma_f32_16x16x32_bf16(a0, wob0, bC, 0, 0, 0);
        hacc = __builtin_amdgcn_mfma_f32_16x16x32_bf16(a1, wob1, hacc, 0, 0, 0);
        if (ln < 2) {
            #pragma unroll
            for (int r = 0; r < 4; ++r) {
                float sp = softplus_(hacc[r]) + 1e-4f;
                obuf[1][31][ln * 16 + qd * 4 + r] = sp * scl4[r];
            }
        }
    }
    __syncthreads();
    #pragma unroll
    for (int h = 0; h < 4; ++h) {
        int e = tid + NT * h;
        int tte = e & 31, rowe = (e >> 5) & 15, pe = e >> 9;
        out[(pe ? (BB * SS) : 0) + (size_t)(b0 + rowe) * SS + 480 + tte] =
            obuf[1][tte][pe * 16 + rowe];
    }
}

extern "C" void kernel_launch(void* const* d_in, const int* in_sizes, int n_in,
                              void* d_out, int out_size, void* d_ws, size_t ws_size,
                              hipStream_t stream) {
    deepar_kernel<<<BB / BT, NT, 0, stream>>>(
        (const float*)d_in[0], (const float*)d_in[1], (const int*)d_in[2],
        (const float*)d_in[3], (const float*)d_in[4], (const float*)d_in[5],
        (const float*)d_in[6], (const float*)d_in[7], (const float*)d_in[8],
        (const float*)d_in[9], (const float*)d_in[10], (const float*)d_in[11],
        (const float*)d_in[12], (float*)d_out);
}

// Round 5
// 514.014 us; speedup vs baseline: 1.6527x; 1.0913x over previous
//
#include <hip/hip_runtime.h>

#define BB 4096
#define SS 512
#define NG 256     // 4*HID gate columns
#define BT 16      // batch rows per workgroup (grid = 256 = #CUs)
#define NT 512     // 8 waves: 0-3 compute (MFMA+cell), 4-7 service (head/stage/flush)
#define CH 32      // time-chunk length
#define HSTR 68    // hbuf row stride (shorts)
#define PSTR 16    // pcx row stride (shorts): slots 0..11 real, 12..15 zero
#define SBSTR 264  // sbias row stride (floats), overlaid on pcx
#define OSTR 33    // obuf row stride (floats)

typedef __bf16 bf16_t;
typedef bf16_t bf16x8 __attribute__((ext_vector_type(8)));
typedef float  f32x4  __attribute__((ext_vector_type(4)));

__device__ __forceinline__ unsigned short f2bf(float x) {
    union { float f; unsigned u; } q{x};
    unsigned r = (q.u + 0x7fffu + ((q.u >> 16) & 1u)) >> 16;
    return (unsigned short)r;
}
__device__ __forceinline__ float bf2f(unsigned short s) {
    union { unsigned u; float f; } q{((unsigned)s) << 16};
    return q.f;
}
#define LOG2E 1.4426950408889634f
__device__ __forceinline__ float frcp_(float x)  { return __builtin_amdgcn_rcpf(x); }
__device__ __forceinline__ float fexp2_(float x) { return __builtin_amdgcn_exp2f(x); }
__device__ __forceinline__ float flog2_(float x) { return __builtin_amdgcn_logf(x); }
__device__ __forceinline__ float softplus_(float x){ return x > 20.0f ? x : 0.6931471805599453f * flog2_(1.0f + fexp2_(LOG2E * x)); }

// K-slot layout (96): 0..63 = h, 64 = prev, 65..74 = cov, 75 = prev residual, 76..95 = 0.
// Gate columns pre-scaled: i,f,o by -log2e; g by -2log2e.
// Fused-denominator cell (7 trans/cell instead of 10; proven in R4, same absmax):
//   ae=e^-i, fe=e^-f, ge=e^-2g, oe=e^-o  (exp2 of prescaled accs, clamped at 30)
//   c' = (c*p + (1-ge)*q) * rcp(p*q),  p=(1+ae)(1+ge), q=(1+fe)
//   h  = (1-d) * rcp((1+oe)(1+d)),     d = exp2(-2log2e*c')
// Waves 0-3: wave wv owns all 4 gates for units 16wv..16wv+15; cell lane-local.
// Wave 4: output head via MFMA. Waves 4-7: chunk staging/flush. One barrier/step.
__global__ __launch_bounds__(NT)
void deepar_kernel(const float* __restrict__ target, const float* __restrict__ cov,
                   const int* __restrict__ cats, const float* __restrict__ scale,
                   const float* __restrict__ emb0, const float* __restrict__ emb1,
                   const float* __restrict__ emb2, const float* __restrict__ emb3,
                   const float* __restrict__ w_ih, const float* __restrict__ w_hh,
                   const float* __restrict__ bias, const float* __restrict__ w_out,
                   const float* __restrict__ b_out, float* __restrict__ out)
{
    // pcx (2*32*16*16 shorts = 32768 B) overlays sbias(16896 B)+sx(4352 B) scratch
    __shared__ __attribute__((aligned(16))) unsigned char smemA[2 * CH * BT * PSTR * 2];
    __shared__ __attribute__((aligned(16))) unsigned short hbuf[2][BT][HSTR]; //  4352 B
    __shared__ float obuf[2][CH][OSTR];                                       //  8448 B
    __shared__ float inv_s[BT], scl_s[BT];

    unsigned short* pcx   = (unsigned short*)smemA;
    float*          sbias = (float*)smemA;
    float*          sx    = (float*)(smemA + BT * SBSTR * 4);

    const int tid  = threadIdx.x;
    const int b0   = blockIdx.x * BT;
    const int lane = tid & 63;
    const int wv   = tid >> 6;
    const int qd   = lane >> 4;
    const int ln   = lane & 15;
    const bool is_compute = (wv < 4);
    const int tid2 = tid & 255;          // index within service half (wv>=4)

    // ---------------- setup ----------------
    for (int i = tid; i < 2 * BT * HSTR; i += NT) ((unsigned short*)hbuf)[i] = 0;
    if (tid < BT) {
        float s = scale[b0 + tid];
        scl_s[tid] = s;
        inv_s[tid] = 1.0f / fmaxf(s, 1e-4f);
        sx[tid * 68 + 64] = log1pf(s);
    }
    if (tid < BT * 4) {
        int r = tid >> 2, e = tid & 3;
        int c = cats[(b0 + r) * 4 + e];
        const float* eb = (e == 0 ? emb0 : e == 1 ? emb1 : e == 2 ? emb2 : emb3);
        for (int j = 0; j < 16; ++j) sx[r * 68 + e * 16 + j] = eb[c * 16 + j];
    }
    __syncthreads();

    // sbias[r][n] = bias[n] + static_x[r] . w_ih[11..75][n]; n = tid&255, rows split by tid>>8
    {
        const int n = tid & 255, half = tid >> 8;
        float bj = bias[n];
        float acc[8];
        #pragma unroll
        for (int r = 0; r < 8; ++r) acc[r] = bj;
        for (int k = 0; k < 65; ++k) {
            float w = w_ih[(11 + k) * NG + n];
            #pragma unroll
            for (int r = 0; r < 8; ++r) acc[r] += sx[(half * 8 + r) * 68 + k] * w;
        }
        #pragma unroll
        for (int r = 0; r < 8; ++r) sbias[(half * 8 + r) * SBSTR + n] = acc[r];
    }
    __syncthreads();

    // ---------------- register-resident weights + sbias fragments (compute waves) ----------------
    // gate scale factors folded into weights/bias
    bf16x8 bfrag[4][3];
    f32x4  sbf[4];
    if (is_compute) {
        #pragma unroll
        for (int ti = 0; ti < 4; ++ti) {
            const float gsc = (ti == 2) ? (-2.0f * LOG2E) : (-LOG2E);
            const int n = ln + 16 * (wv + 4 * ti);   // gate ti, unit 16wv+ln
            #pragma unroll
            for (int c = 0; c < 3; ++c) {
                #pragma unroll
                for (int j = 0; j < 8; ++j) {
                    int k = qd * 8 + 32 * c + j;
                    float w;
                    if (k < 64)                  w = w_hh[k * NG + n];
                    else if (k == 64 || k == 75) w = w_ih[n];
                    else if (k <= 74)            w = w_ih[(k - 64) * NG + n];
                    else                         w = 0.0f;
                    bfrag[ti][c][j] = (bf16_t)(w * gsc);
                }
            }
            #pragma unroll
            for (int r = 0; r < 4; ++r)
                sbf[ti][r] = sbias[(qd * 4 + r) * SBSTR + n] * gsc;
        }
    }

    // head fragments (used by wave 4): B = w_out padded to 16 cols, C = b_out
    bf16x8 wob0, wob1;
    f32x4  bC;
    float  scl4[4];
    #pragma unroll
    for (int j = 0; j < 8; ++j) {
        wob0[j] = (bf16_t)((ln < 2) ? w_out[(qd * 8 + j) * 2 + ln] : 0.0f);
        wob1[j] = (bf16_t)((ln < 2) ? w_out[(32 + qd * 8 + j) * 2 + ln] : 0.0f);
    }
    #pragma unroll
    for (int r = 0; r < 4; ++r) {
        bC[r]   = (ln < 2) ? b_out[ln] : 0.0f;
        scl4[r] = (ln == 0) ? scl_s[qd * 4 + r] : 1.0f;   // mus scaled, alphas not
    }

    __syncthreads();   // all sbias/sx reads done -> safe to overwrite with pcx

    // zero pcx (both buffers; establishes the permanent-zero slots 12..15)
    for (int i = tid; i < (2 * CH * BT * PSTR) / 2; i += NT) ((int*)smemA)[i] = 0;
    __syncthreads();

    // fill pcx chunk 0 (steps 0..31)
    if (tid < 256) {
        const int row = tid >> 4, i5 = tid & 15;
        const float* cr = cov + (size_t)(b0 + row) * (SS * 10);
        #pragma unroll
        for (int j = 0; j < 20; ++j) {
            int e = i5 + 16 * j, tp = e / 10, k = e - 10 * tp;
            pcx[((0 * CH + tp) * BT + row) * PSTR + 1 + k] = f2bf(cr[e]);
        }
        float pv0 = (i5 == 0) ? 0.0f : target[(size_t)(b0 + row) * SS + i5 - 1] * inv_s[row];
        float pv1 = target[(size_t)(b0 + row) * SS + i5 + 15] * inv_s[row];
        unsigned short m0 = f2bf(pv0), m1 = f2bf(pv1);
        pcx[((0 * CH + i5) * BT + row) * PSTR + 0]       = m0;
        pcx[((0 * CH + i5) * BT + row) * PSTR + 11]      = f2bf(pv0 - bf2f(m0));
        pcx[((0 * CH + i5 + 16) * BT + row) * PSTR + 0]  = m1;
        pcx[((0 * CH + i5 + 16) * BT + row) * PSTR + 11] = f2bf(pv1 - bf2f(m1));
    }
    __syncthreads();

    // prime a2(0) and acc_pre(0) = x-part of gates for t=0 (compute waves)
    bf16x8 a2 = {};
    f32x4 acc_pre[4];
    if (is_compute) {
        if (qd < 2)
            a2 = *(const bf16x8*)&pcx[((0 * CH + 0) * BT + ln) * PSTR + qd * 8];
        #pragma unroll
        for (int ti = 0; ti < 4; ++ti)
            acc_pre[ti] = __builtin_amdgcn_mfma_f32_16x16x32_bf16(a2, bfrag[ti][2], sbf[ti], 0, 0, 0);
    }

    float cst[4] = {0.0f, 0.0f, 0.0f, 0.0f};
    float crg[20];
    #pragma unroll
    for (int j = 0; j < 20; ++j) crg[j] = 0.0f;
    float trg0 = 0.0f, trg1 = 0.0f;

    // ---------------- time loop (ONE barrier per step) ----------------
    for (int t = 0; t < SS; ++t) {
        const int cur = t & 1, nxt = cur ^ 1;
        __syncthreads();   // hbuf[cur] complete; acc_pre already holds x-part of gates(t)

        if (is_compute) {
            // ---- recurrence waves: 2-deep MFMA chain + lane-local cell ----
            const unsigned short* hb = &hbuf[cur][ln][0];
            bf16x8 a0 = *(const bf16x8*)(hb + qd * 8);
            bf16x8 a1 = *(const bf16x8*)(hb + 32 + qd * 8);

            f32x4 acc0 = __builtin_amdgcn_mfma_f32_16x16x32_bf16(a0, bfrag[0][0], acc_pre[0], 0, 0, 0);
            f32x4 acc1 = __builtin_amdgcn_mfma_f32_16x16x32_bf16(a0, bfrag[1][0], acc_pre[1], 0, 0, 0);
            f32x4 acc2 = __builtin_amdgcn_mfma_f32_16x16x32_bf16(a0, bfrag[2][0], acc_pre[2], 0, 0, 0);
            f32x4 acc3 = __builtin_amdgcn_mfma_f32_16x16x32_bf16(a0, bfrag[3][0], acc_pre[3], 0, 0, 0);
            acc0 = __builtin_amdgcn_mfma_f32_16x16x32_bf16(a1, bfrag[0][1], acc0, 0, 0, 0);
            acc1 = __builtin_amdgcn_mfma_f32_16x16x32_bf16(a1, bfrag[1][1], acc1, 0, 0, 0);
            acc2 = __builtin_amdgcn_mfma_f32_16x16x32_bf16(a1, bfrag[2][1], acc2, 0, 0, 0);
            acc3 = __builtin_amdgcn_mfma_f32_16x16x32_bf16(a1, bfrag[3][1], acc3, 0, 0, 0);

            // prefetch a2 for t+1 (pcx stable; committed >=15 steps earlier)
            if (t + 1 < SS && qd < 2)
                a2 = *(const bf16x8*)&pcx[((((t + 1) >> 5) & 1) * CH + ((t + 1) & 31)) * BT * PSTR
                                          + ln * PSTR + qd * 8];

            // ---- fused-denominator LSTM cell: unit u = 16wv+ln, rows qd*4+r ----
            // acc0/1/3 = -log2e * (i,f,o preact); acc2 = -2log2e * g preact
            const int u = 16 * wv + ln;
            #pragma unroll
            for (int r = 0; r < 4; ++r) {
                float ae = fexp2_(fminf(acc0[r], 30.0f));   // e^-i
                float fe = fexp2_(fminf(acc1[r], 30.0f));   // e^-f
                float ge = fexp2_(fminf(acc2[r], 30.0f));   // e^-2g
                float oe = fexp2_(fminf(acc3[r], 30.0f));   // e^-o
                float p  = (1.0f + ae) * (1.0f + ge);
                float q  = 1.0f + fe;
                float cc = (cst[r] * p + (1.0f - ge) * q) * frcp_(p * q);
                cst[r] = cc;
                float d  = fexp2_(fminf((-2.0f * LOG2E) * cc, 30.0f));
                float hv = (1.0f - d) * frcp_((1.0f + oe) * (1.0f + d));
                *(bf16_t*)&hbuf[nxt][qd * 4 + r][u] = (bf16_t)hv;
            }

            // x-part of gates for t+1 (independent of h; executes under the barrier wait)
            if (t + 1 < SS) {
                #pragma unroll
                for (int ti = 0; ti < 4; ++ti)
                    acc_pre[ti] = __builtin_amdgcn_mfma_f32_16x16x32_bf16(a2, bfrag[ti][2], sbf[ti], 0, 0, 0);
            }
        } else {
            // ---- service waves ----
            if ((t & 31) == 0 && t < 480) {
                const int row = tid2 >> 4, i5 = tid2 & 15, t0n = t + CH;
                const float* cr = cov + (size_t)(b0 + row) * (SS * 10) + t0n * 10;
                #pragma unroll
                for (int j = 0; j < 20; ++j) crg[j] = cr[i5 + 16 * j];
                const float* tr = target + (size_t)(b0 + row) * SS + t0n + i5;
                trg0 = tr[-1];
                trg1 = tr[15];
            }

            // head for t-1 via MFMA on wave 4 (reads h_{t-1} fragments; no shfl chain)
            if (wv == 4 && t > 0) {
                const unsigned short* hb = &hbuf[cur][ln][0];
                bf16x8 a0 = *(const bf16x8*)(hb + qd * 8);
                bf16x8 a1 = *(const bf16x8*)(hb + 32 + qd * 8);
                f32x4 hacc = __builtin_amdgcn_mfma_f32_16x16x32_bf16(a0, wob0, bC, 0, 0, 0);
                hacc = __builtin_amdgcn_mfma_f32_16x16x32_bf16(a1, wob1, hacc, 0, 0, 0);
                if (ln < 2) {
                    #pragma unroll
                    for (int r = 0; r < 4; ++r) {
                        float sp = softplus_(hacc[r]) + 1e-4f;
                        obuf[((t - 1) >> 5) & 1][(t - 1) & 31][ln * 16 + qd * 4 + r] = sp * scl4[r];
                    }
                }
            }

            if ((t & 31) == 16) {
                const int c = t >> 5;
                if (c < 15) {
                    const int row = tid2 >> 4, i5 = tid2 & 15, nb = (c + 1) & 1;
                    float pv0 = trg0 * inv_s[row];
                    float pv1 = trg1 * inv_s[row];
                    unsigned short m0 = f2bf(pv0), m1 = f2bf(pv1);
                    pcx[((nb * CH + i5) * BT + row) * PSTR + 0]       = m0;
                    pcx[((nb * CH + i5) * BT + row) * PSTR + 11]      = f2bf(pv0 - bf2f(m0));
                    pcx[((nb * CH + i5 + 16) * BT + row) * PSTR + 0]  = m1;
                    pcx[((nb * CH + i5 + 16) * BT + row) * PSTR + 11] = f2bf(pv1 - bf2f(m1));
                    #pragma unroll
                    for (int j = 0; j < 20; ++j) {
                        int e = i5 + 16 * j, tp = e / 10, k = e - 10 * tp;
                        pcx[((nb * CH + tp) * BT + row) * PSTR + 1 + k] = f2bf(crg[j]);
                    }
                }
                if (c >= 1) {
                    const int pb = (c - 1) & 1, t0p = (c - 1) << 5;
                    #pragma unroll
                    for (int h = 0; h < 4; ++h) {
                        int e = tid2 + 256 * h;
                        int tte = e & 31, rowe = (e >> 5) & 15, pe = e >> 9;
                        out[(pe ? (BB * SS) : 0) + (size_t)(b0 + rowe) * SS + t0p + tte] =
                            obuf[pb][tte][pe * 16 + rowe];
                    }
                }
            }
        }
    }

    // ---------------- epilogue: head for t=511 (h in hbuf[0]) + flush chunk 15 ----------------
    __syncthreads();
    if (wv == 4) {
        const unsigned short* hb = &hbuf[0][ln][0];
        bf16x8 a0 = *(const bf16x8*)(hb + qd * 8);
        bf16x8 a1 = *(const bf16x8*)(hb + 32 + qd * 8);
        f32x4 hacc = __builtin_amdgcn_mfma_f32_16x16x32_bf16(a0, wob0, bC, 0, 0, 0);
        hacc = __builtin_amdgcn_mfma_f32_16x16x32_bf16(a1, wob1, hacc, 0, 0, 0);
        if (ln < 2) {
            #pragma unroll
            for (int r = 0; r < 4; ++r) {
                float sp = softplus_(hacc[r]) + 1e-4f;
                obuf[1][31][ln * 16 + qd * 4 + r] = sp * scl4[r];
            }
        }
    }
    __syncthreads();
    #pragma unroll
    for (int h = 0; h < 2; ++h) {
        int e = tid + NT * h;
        int tte = e & 31, rowe = (e >> 5) & 15, pe = e >> 9;
        out[(pe ? (BB * SS) : 0) + (size_t)(b0 + rowe) * SS + 480 + tte] =
            obuf[1][tte][pe * 16 + rowe];
    }
}

extern "C" void kernel_launch(void* const* d_in, const int* in_sizes, int n_in,
                              void* d_out, int out_size, void* d_ws, size_t ws_size,
                              hipStream_t stream) {
    deepar_kernel<<<BB / BT, NT, 0, stream>>>(
        (const float*)d_in[0], (const float*)d_in[1], (const int*)d_in[2],
        (const float*)d_in[3], (const float*)d_in[4], (const float*)d_in[5],
        (const float*)d_in[6], (const float*)d_in[7], (const float*)d_in[8],
        (const float*)d_in[9], (const float*)d_in[10], (const float*)d_in[11],
        (const float*)d_in[12], (float*)d_out);
}

// Round 6
// 496.277 us; speedup vs baseline: 1.7118x; 1.0357x over previous
//
#include <hip/hip_runtime.h>

#define BB 4096
#define SS 512
#define NG 256     // 4*HID gate columns
#define BT 16      // batch rows per workgroup (grid = 256 = #CUs)
#define NT 512     // 8 waves: 0-3 compute (MFMA+cell), 4-7 service (head/stage/flush)
#define CH 32      // time-chunk length
#define HSTR 68    // hbuf row stride (shorts)
#define PSTR 16    // pcx row stride (shorts): slots 0..11 real, 12..15 zero
#define SBSTR 264  // sbias row stride (floats), overlaid on pcx
#define OSTR 33    // obuf row stride (floats)

typedef __bf16 bf16_t;
typedef bf16_t bf16x8 __attribute__((ext_vector_type(8)));
typedef float  f32x4  __attribute__((ext_vector_type(4)));

__device__ __forceinline__ unsigned short f2bf(float x) {
    union { float f; unsigned u; } q{x};
    unsigned r = (q.u + 0x7fffu + ((q.u >> 16) & 1u)) >> 16;
    return (unsigned short)r;
}
__device__ __forceinline__ float bf2f(unsigned short s) {
    union { unsigned u; float f; } q{((unsigned)s) << 16};
    return q.f;
}
#define LOG2E 1.4426950408889634f
__device__ __forceinline__ float frcp_(float x)  { return __builtin_amdgcn_rcpf(x); }
__device__ __forceinline__ float fexp2_(float x) { return __builtin_amdgcn_exp2f(x); }
__device__ __forceinline__ float flog2_(float x) { return __builtin_amdgcn_logf(x); }
__device__ __forceinline__ float softplus_(float x){ return x > 20.0f ? x : 0.6931471805599453f * flog2_(1.0f + fexp2_(LOG2E * x)); }

// lgkm-only barrier: orders all LDS traffic (hbuf/pcx/obuf) across the step
// WITHOUT draining vmcnt — service waves' chunk global loads (t%32==0) and
// out[] stores (t%32==16) stay in flight across barriers instead of exposing
// ~500-900 cyc of HBM latency to the whole block at the next step.
__device__ __forceinline__ void bar_lgkm() {
    asm volatile("s_waitcnt lgkmcnt(0)\n\ts_barrier" ::: "memory");
}

// K-slot layout (96): 0..63 = h, 64 = prev, 65..74 = cov, 75 = prev residual, 76..95 = 0.
// Gate columns pre-scaled: i,f,o by -log2e; g by -2log2e, so the cell needs no pre-mul:
//   sigma(x) = rcp(1+exp2(y)),  tanh(x) = 2*rcp(1+exp2(z)) - 1.
// Waves 0-3: wave wv owns all 4 gates for units 16wv..16wv+15; cell lane-local.
// Wave 4: output head via MFMA. Waves 4-7: chunk staging/flush. One barrier/step.
// Compute waves run at s_setprio(1): wave 4 (head) shares SIMD0 with compute
// wave 0; priority split makes the head issue into wave 0's stall slots instead
// of stealing live slots (T5 role-split regime), de-stretching the per-step
// barrier straggler.
__global__ __launch_bounds__(NT)
void deepar_kernel(const float* __restrict__ target, const float* __restrict__ cov,
                   const int* __restrict__ cats, const float* __restrict__ scale,
                   const float* __restrict__ emb0, const float* __restrict__ emb1,
                   const float* __restrict__ emb2, const float* __restrict__ emb3,
                   const float* __restrict__ w_ih, const float* __restrict__ w_hh,
                   const float* __restrict__ bias, const float* __restrict__ w_out,
                   const float* __restrict__ b_out, float* __restrict__ out)
{
    // pcx (2*32*16*16 shorts = 32768 B) overlays sbias(16896 B)+sx(4352 B) scratch
    __shared__ __attribute__((aligned(16))) unsigned char smemA[2 * CH * BT * PSTR * 2];
    __shared__ __attribute__((aligned(16))) unsigned short hbuf[2][BT][HSTR]; //  4352 B
    __shared__ float obuf[2][CH][OSTR];                                       //  8448 B
    __shared__ float inv_s[BT], scl_s[BT];

    unsigned short* pcx   = (unsigned short*)smemA;
    float*          sbias = (float*)smemA;
    float*          sx    = (float*)(smemA + BT * SBSTR * 4);

    const int tid  = threadIdx.x;
    const int b0   = blockIdx.x * BT;
    const int lane = tid & 63;
    const int wv   = tid >> 6;
    const int qd   = lane >> 4;
    const int ln   = lane & 15;
    const bool is_compute = (wv < 4);
    const int tid2 = tid & 255;          // index within service half (wv>=4)

    // ---------------- setup ----------------
    for (int i = tid; i < 2 * BT * HSTR; i += NT) ((unsigned short*)hbuf)[i] = 0;
    if (tid < BT) {
        float s = scale[b0 + tid];
        scl_s[tid] = s;
        inv_s[tid] = 1.0f / fmaxf(s, 1e-4f);
        sx[tid * 68 + 64] = log1pf(s);
    }
    if (tid < BT * 4) {
        int r = tid >> 2, e = tid & 3;
        int c = cats[(b0 + r) * 4 + e];
        const float* eb = (e == 0 ? emb0 : e == 1 ? emb1 : e == 2 ? emb2 : emb3);
        for (int j = 0; j < 16; ++j) sx[r * 68 + e * 16 + j] = eb[c * 16 + j];
    }
    __syncthreads();

    // sbias[r][n] = bias[n] + static_x[r] . w_ih[11..75][n]; n = tid&255, rows split by tid>>8
    {
        const int n = tid & 255, half = tid >> 8;
        float bj = bias[n];
        float acc[8];
        #pragma unroll
        for (int r = 0; r < 8; ++r) acc[r] = bj;
        for (int k = 0; k < 65; ++k) {
            float w = w_ih[(11 + k) * NG + n];
            #pragma unroll
            for (int r = 0; r < 8; ++r) acc[r] += sx[(half * 8 + r) * 68 + k] * w;
        }
        #pragma unroll
        for (int r = 0; r < 8; ++r) sbias[(half * 8 + r) * SBSTR + n] = acc[r];
    }
    __syncthreads();

    // ---------------- register-resident weights + sbias fragments (compute waves) ----------------
    // gate scale factors folded into weights/bias
    bf16x8 bfrag[4][3];
    f32x4  sbf[4];
    if (is_compute) {
        #pragma unroll
        for (int ti = 0; ti < 4; ++ti) {
            const float gsc = (ti == 2) ? (-2.0f * LOG2E) : (-LOG2E);
            const int n = ln + 16 * (wv + 4 * ti);   // gate ti, unit 16wv+ln
            #pragma unroll
            for (int c = 0; c < 3; ++c) {
                #pragma unroll
                for (int j = 0; j < 8; ++j) {
                    int k = qd * 8 + 32 * c + j;
                    float w;
                    if (k < 64)                  w = w_hh[k * NG + n];
                    else if (k == 64 || k == 75) w = w_ih[n];
                    else if (k <= 74)            w = w_ih[(k - 64) * NG + n];
                    else                         w = 0.0f;
                    bfrag[ti][c][j] = (bf16_t)(w * gsc);
                }
            }
            #pragma unroll
            for (int r = 0; r < 4; ++r)
                sbf[ti][r] = sbias[(qd * 4 + r) * SBSTR + n] * gsc;
        }
    }

    // head fragments (used by wave 4): B = w_out padded to 16 cols, C = b_out
    bf16x8 wob0, wob1;
    f32x4  bC;
    float  scl4[4];
    #pragma unroll
    for (int j = 0; j < 8; ++j) {
        wob0[j] = (bf16_t)((ln < 2) ? w_out[(qd * 8 + j) * 2 + ln] : 0.0f);
        wob1[j] = (bf16_t)((ln < 2) ? w_out[(32 + qd * 8 + j) * 2 + ln] : 0.0f);
    }
    #pragma unroll
    for (int r = 0; r < 4; ++r) {
        bC[r]   = (ln < 2) ? b_out[ln] : 0.0f;
        scl4[r] = (ln == 0) ? scl_s[qd * 4 + r] : 1.0f;   // mus scaled, alphas not
    }

    __syncthreads();   // all sbias/sx reads done -> safe to overwrite with pcx

    // zero pcx (both buffers; establishes the permanent-zero slots 12..15)
    for (int i = tid; i < (2 * CH * BT * PSTR) / 2; i += NT) ((int*)smemA)[i] = 0;
    __syncthreads();

    // fill pcx chunk 0 (steps 0..31)
    if (tid < 256) {
        const int row = tid >> 4, i5 = tid & 15;
        const float* cr = cov + (size_t)(b0 + row) * (SS * 10);
        #pragma unroll
        for (int j = 0; j < 20; ++j) {
            int e = i5 + 16 * j, tp = e / 10, k = e - 10 * tp;
            pcx[((0 * CH + tp) * BT + row) * PSTR + 1 + k] = f2bf(cr[e]);
        }
        float pv0 = (i5 == 0) ? 0.0f : target[(size_t)(b0 + row) * SS + i5 - 1] * inv_s[row];
        float pv1 = target[(size_t)(b0 + row) * SS + i5 + 15] * inv_s[row];
        unsigned short m0 = f2bf(pv0), m1 = f2bf(pv1);
        pcx[((0 * CH + i5) * BT + row) * PSTR + 0]       = m0;
        pcx[((0 * CH + i5) * BT + row) * PSTR + 11]      = f2bf(pv0 - bf2f(m0));
        pcx[((0 * CH + i5 + 16) * BT + row) * PSTR + 0]  = m1;
        pcx[((0 * CH + i5 + 16) * BT + row) * PSTR + 11] = f2bf(pv1 - bf2f(m1));
    }
    __syncthreads();

    // prime a2(0) and acc_pre(0) = x-part of gates for t=0 (compute waves)
    bf16x8 a2 = {};
    f32x4 acc_pre[4];
    if (is_compute) {
        if (qd < 2)
            a2 = *(const bf16x8*)&pcx[((0 * CH + 0) * BT + ln) * PSTR + qd * 8];
        #pragma unroll
        for (int ti = 0; ti < 4; ++ti)
            acc_pre[ti] = __builtin_amdgcn_mfma_f32_16x16x32_bf16(a2, bfrag[ti][2], sbf[ti], 0, 0, 0);
        __builtin_amdgcn_s_setprio(1);   // compute waves outrank service waves for issue
    }

    float cst[4] = {0.0f, 0.0f, 0.0f, 0.0f};
    float crg[20];
    #pragma unroll
    for (int j = 0; j < 20; ++j) crg[j] = 0.0f;
    float trg0 = 0.0f, trg1 = 0.0f;

    // ---------------- time loop (ONE lgkm-only barrier per step) ----------------
    for (int t = 0; t < SS; ++t) {
        const int cur = t & 1, nxt = cur ^ 1;
        bar_lgkm();        // hbuf[cur] complete; acc_pre already holds x-part of gates(t)

        if (is_compute) {
            // ---- recurrence waves: 2-deep MFMA chain + lane-local cell ----
            const unsigned short* hb = &hbuf[cur][ln][0];
            bf16x8 a0 = *(const bf16x8*)(hb + qd * 8);
            bf16x8 a1 = *(const bf16x8*)(hb + 32 + qd * 8);

            f32x4 acc0 = __builtin_amdgcn_mfma_f32_16x16x32_bf16(a0, bfrag[0][0], acc_pre[0], 0, 0, 0);
            f32x4 acc1 = __builtin_amdgcn_mfma_f32_16x16x32_bf16(a0, bfrag[1][0], acc_pre[1], 0, 0, 0);
            f32x4 acc2 = __builtin_amdgcn_mfma_f32_16x16x32_bf16(a0, bfrag[2][0], acc_pre[2], 0, 0, 0);
            f32x4 acc3 = __builtin_amdgcn_mfma_f32_16x16x32_bf16(a0, bfrag[3][0], acc_pre[3], 0, 0, 0);
            acc0 = __builtin_amdgcn_mfma_f32_16x16x32_bf16(a1, bfrag[0][1], acc0, 0, 0, 0);
            acc1 = __builtin_amdgcn_mfma_f32_16x16x32_bf16(a1, bfrag[1][1], acc1, 0, 0, 0);
            acc2 = __builtin_amdgcn_mfma_f32_16x16x32_bf16(a1, bfrag[2][1], acc2, 0, 0, 0);
            acc3 = __builtin_amdgcn_mfma_f32_16x16x32_bf16(a1, bfrag[3][1], acc3, 0, 0, 0);

            // prefetch a2 for t+1 (pcx stable; committed >=15 steps earlier)
            if (t + 1 < SS && qd < 2)
                a2 = *(const bf16x8*)&pcx[((((t + 1) >> 5) & 1) * CH + ((t + 1) & 31)) * BT * PSTR
                                          + ln * PSTR + qd * 8];

            // lane-local LSTM cell: unit u = 16wv+ln, rows qd*4+r
            // acc0/1/3 = -log2e * (i,f,o preact); acc2 = -2log2e * g preact
            const int u = 16 * wv + ln;
            #pragma unroll
            for (int r = 0; r < 4; ++r) {
                float si = frcp_(1.0f + fexp2_(acc0[r]));
                float sf = frcp_(1.0f + fexp2_(acc1[r]));
                float tg = 2.0f * frcp_(1.0f + fexp2_(acc2[r])) - 1.0f;
                float so = frcp_(1.0f + fexp2_(acc3[r]));
                float cc = sf * cst[r] + si * tg;
                cst[r] = cc;
                float th = 2.0f * frcp_(1.0f + fexp2_((-2.0f * LOG2E) * cc)) - 1.0f;
                *(bf16_t*)&hbuf[nxt][qd * 4 + r][u] = (bf16_t)(so * th);
            }

            // x-part of gates for t+1 (independent of h; executes under the barrier wait)
            if (t + 1 < SS) {
                #pragma unroll
                for (int ti = 0; ti < 4; ++ti)
                    acc_pre[ti] = __builtin_amdgcn_mfma_f32_16x16x32_bf16(a2, bfrag[ti][2], sbf[ti], 0, 0, 0);
            }
        } else {
            // ---- service waves ----
            if ((t & 31) == 0 && t < 480) {
                const int row = tid2 >> 4, i5 = tid2 & 15, t0n = t + CH;
                const float* cr = cov + (size_t)(b0 + row) * (SS * 10) + t0n * 10;
                #pragma unroll
                for (int j = 0; j < 20; ++j) crg[j] = cr[i5 + 16 * j];
                const float* tr = target + (size_t)(b0 + row) * SS + t0n + i5;
                trg0 = tr[-1];
                trg1 = tr[15];
            }

            // head for t-1 via MFMA on wave 4 (reads h_{t-1} fragments; no shfl chain)
            if (wv == 4 && t > 0) {
                const unsigned short* hb = &hbuf[cur][ln][0];
                bf16x8 a0 = *(const bf16x8*)(hb + qd * 8);
                bf16x8 a1 = *(const bf16x8*)(hb + 32 + qd * 8);
                f32x4 hacc = __builtin_amdgcn_mfma_f32_16x16x32_bf16(a0, wob0, bC, 0, 0, 0);
                hacc = __builtin_amdgcn_mfma_f32_16x16x32_bf16(a1, wob1, hacc, 0, 0, 0);
                if (ln < 2) {
                    #pragma unroll
                    for (int r = 0; r < 4; ++r) {
                        float sp = softplus_(hacc[r]) + 1e-4f;
                        obuf[((t - 1) >> 5) & 1][(t - 1) & 31][ln * 16 + qd * 4 + r] = sp * scl4[r];
                    }
                }
            }

            if ((t & 31) == 16) {
                const int c = t >> 5;
                if (c < 15) {
                    const int row = tid2 >> 4, i5 = tid2 & 15, nb = (c + 1) & 1;
                    float pv0 = trg0 * inv_s[row];
                    float pv1 = trg1 * inv_s[row];
                    unsigned short m0 = f2bf(pv0), m1 = f2bf(pv1);
                    pcx[((nb * CH + i5) * BT + row) * PSTR + 0]       = m0;
                    pcx[((nb * CH + i5) * BT + row) * PSTR + 11]      = f2bf(pv0 - bf2f(m0));
                    pcx[((nb * CH + i5 + 16) * BT + row) * PSTR + 0]  = m1;
                    pcx[((nb * CH + i5 + 16) * BT + row) * PSTR + 11] = f2bf(pv1 - bf2f(m1));
                    #pragma unroll
                    for (int j = 0; j < 20; ++j) {
                        int e = i5 + 16 * j, tp = e / 10, k = e - 10 * tp;
                        pcx[((nb * CH + tp) * BT + row) * PSTR + 1 + k] = f2bf(crg[j]);
                    }
                }
                if (c >= 1) {
                    const int pb = (c - 1) & 1, t0p = (c - 1) << 5;
                    #pragma unroll
                    for (int h = 0; h < 4; ++h) {
                        int e = tid2 + 256 * h;
                        int tte = e & 31, rowe = (e >> 5) & 15, pe = e >> 9;
                        out[(pe ? (BB * SS) : 0) + (size_t)(b0 + rowe) * SS + t0p + tte] =
                            obuf[pb][tte][pe * 16 + rowe];
                    }
                }
            }
        }
    }

    // ---------------- epilogue: head for t=511 (h in hbuf[0]) + flush chunk 15 ----------------
    __syncthreads();
    if (wv == 4) {
        const unsigned short* hb = &hbuf[0][ln][0];
        bf16x8 a0 = *(const bf16x8*)(hb + qd * 8);
        bf16x8 a1 = *(const bf16x8*)(hb + 32 + qd * 8);
        f32x4 hacc = __builtin_amdgcn_mfma_f32_16x16x32_bf16(a0, wob0, bC, 0, 0, 0);
        hacc = __builtin_amdgcn_mfma_f32_16x16x32_bf16(a1, wob1, hacc, 0, 0, 0);
        if (ln < 2) {
            #pragma unroll
            for (int r = 0; r < 4; ++r) {
                float sp = softplus_(hacc[r]) + 1e-4f;
                obuf[1][31][ln * 16 + qd * 4 + r] = sp * scl4[r];
            }
        }
    }
    __syncthreads();
    #pragma unroll
    for (int h = 0; h < 2; ++h) {
        int e = tid + NT * h;
        int tte = e & 31, rowe = (e >> 5) & 15, pe = e >> 9;
        out[(pe ? (BB * SS) : 0) + (size_t)(b0 + rowe) * SS + 480 + tte] =
            obuf[1][tte][pe * 16 + rowe];
    }
}

extern "C" void kernel_launch(void* const* d_in, const int* in_sizes, int n_in,
                              void* d_out, int out_size, void* d_ws, size_t ws_size,
                              hipStream_t stream) {
    deepar_kernel<<<BB / BT, NT, 0, stream>>>(
        (const float*)d_in[0], (const float*)d_in[1], (const int*)d_in[2],
        (const float*)d_in[3], (const float*)d_in[4], (const float*)d_in[5],
        (const float*)d_in[6], (const float*)d_in[7], (const float*)d_in[8],
        (const float*)d_in[9], (const float*)d_in[10], (const float*)d_in[11],
        (const float*)d_in[12], (float*)d_out);
}

// Round 7
// 490.246 us; speedup vs baseline: 1.7328x; 1.0123x over previous
//
#include <hip/hip_runtime.h>

#define BB 4096
#define SS 512
#define NG 256     // 4*HID gate columns
#define BT 16      // batch rows per workgroup (grid = 256 = #CUs)
#define NT 512     // 8 waves: 0-3 compute (MFMA+cell), 4-7 service (head/stage/flush)
#define CH 32      // time-chunk length
#define HSTR 68    // hbuf row stride (shorts)
#define PSTR 16    // pcx row stride (shorts): slots 0..11 real, 12..15 zero
#define SBSTR 264  // sbias row stride (floats), overlaid on pcx
#define OSTR 33    // obuf row stride (floats)

typedef __bf16 bf16_t;
typedef bf16_t bf16x8 __attribute__((ext_vector_type(8)));
typedef bf16_t bf16x4 __attribute__((ext_vector_type(4)));
typedef float  f32x4  __attribute__((ext_vector_type(4)));

__device__ __forceinline__ unsigned short f2bf(float x) {
    union { float f; unsigned u; } q{x};
    unsigned r = (q.u + 0x7fffu + ((q.u >> 16) & 1u)) >> 16;
    return (unsigned short)r;
}
__device__ __forceinline__ float bf2f(unsigned short s) {
    union { unsigned u; float f; } q{((unsigned)s) << 16};
    return q.f;
}
#define LOG2E 1.4426950408889634f
__device__ __forceinline__ float frcp_(float x)  { return __builtin_amdgcn_rcpf(x); }
__device__ __forceinline__ float fexp2_(float x) { return __builtin_amdgcn_exp2f(x); }
__device__ __forceinline__ float flog2_(float x) { return __builtin_amdgcn_logf(x); }
__device__ __forceinline__ float softplus_(float x){ return x > 20.0f ? x : 0.6931471805599453f * flog2_(1.0f + fexp2_(LOG2E * x)); }

// lgkm-only barrier: orders all LDS traffic WITHOUT draining vmcnt — service
// waves' global loads/stores stay in flight across barriers.
__device__ __forceinline__ void bar_lgkm() {
    asm volatile("s_waitcnt lgkmcnt(0)\n\ts_barrier" ::: "memory");
}

// K-slot layout (96): 0..63 = h, 64 = prev, 65..74 = cov, 75 = prev residual, 76..95 = 0.
// Gate columns pre-scaled: i,f,o by -log2e; g by -2log2e:
//   sigma(x) = rcp(1+exp2(y)),  tanh(x) = 2*rcp(1+exp2(z)) - 1.
//
// SWAPPED-OPERAND GEMM (this round's change): gates^T = mfma(W_frag, h_frag, C).
// A/B fragment layouts are mirrored (row/col = lane&15, k = (lane>>4)*8+j), so
// the SAME weight registers serve as the A operand and the SAME hbuf b128 reads
// serve as B. Output C flips to D[unit_local][batch]: lane(qd,ln) owns gate
// preacts for units 16wv+qd*4..+3 of batch row ln -> the 4 h values are
// CONSECUTIVE units of one hbuf row -> ONE ds_write_b64 instead of four
// ds_write_b16. Cuts the CU LDS-pipe occupancy (the R1/R3-validated
// bottleneck) by ~70 cyc/step. Bitwise-identical math.
// Waves 0-3 compute; wave 4 head (same swap); waves 4-7 staging/flush
// (commit at t%32==8, flush at t%32==16 so the peaks don't collide).
__global__ __launch_bounds__(NT)
void deepar_kernel(const float* __restrict__ target, const float* __restrict__ cov,
                   const int* __restrict__ cats, const float* __restrict__ scale,
                   const float* __restrict__ emb0, const float* __restrict__ emb1,
                   const float* __restrict__ emb2, const float* __restrict__ emb3,
                   const float* __restrict__ w_ih, const float* __restrict__ w_hh,
                   const float* __restrict__ bias, const float* __restrict__ w_out,
                   const float* __restrict__ b_out, float* __restrict__ out)
{
    // pcx (2*32*16*16 shorts = 32768 B) overlays sbias(16896 B)+sx(4352 B) scratch
    __shared__ __attribute__((aligned(16))) unsigned char smemA[2 * CH * BT * PSTR * 2];
    __shared__ __attribute__((aligned(16))) unsigned short hbuf[2][BT][HSTR]; //  4352 B
    __shared__ float obuf[2][CH][OSTR];                                       //  8448 B
    __shared__ float inv_s[BT], scl_s[BT];

    unsigned short* pcx   = (unsigned short*)smemA;
    float*          sbias = (float*)smemA;
    float*          sx    = (float*)(smemA + BT * SBSTR * 4);

    const int tid  = threadIdx.x;
    const int b0   = blockIdx.x * BT;
    const int lane = tid & 63;
    const int wv   = tid >> 6;
    const int qd   = lane >> 4;
    const int ln   = lane & 15;
    const bool is_compute = (wv < 4);
    const int tid2 = tid & 255;          // index within service half (wv>=4)

    // ---------------- setup ----------------
    for (int i = tid; i < 2 * BT * HSTR; i += NT) ((unsigned short*)hbuf)[i] = 0;
    if (tid < BT) {
        float s = scale[b0 + tid];
        scl_s[tid] = s;
        inv_s[tid] = 1.0f / fmaxf(s, 1e-4f);
        sx[tid * 68 + 64] = log1pf(s);
    }
    if (tid < BT * 4) {
        int r = tid >> 2, e = tid & 3;
        int c = cats[(b0 + r) * 4 + e];
        const float* eb = (e == 0 ? emb0 : e == 1 ? emb1 : e == 2 ? emb2 : emb3);
        for (int j = 0; j < 16; ++j) sx[r * 68 + e * 16 + j] = eb[c * 16 + j];
    }
    __syncthreads();

    // sbias[r][n] = bias[n] + static_x[r] . w_ih[11..75][n]; n = tid&255, rows split by tid>>8
    {
        const int n = tid & 255, half = tid >> 8;
        float bj = bias[n];
        float acc[8];
        #pragma unroll
        for (int r = 0; r < 8; ++r) acc[r] = bj;
        for (int k = 0; k < 65; ++k) {
            float w = w_ih[(11 + k) * NG + n];
            #pragma unroll
            for (int r = 0; r < 8; ++r) acc[r] += sx[(half * 8 + r) * 68 + k] * w;
        }
        #pragma unroll
        for (int r = 0; r < 8; ++r) sbias[(half * 8 + r) * SBSTR + n] = acc[r];
    }
    __syncthreads();

    // ---------------- register-resident weights + sbias fragments (compute waves) ----------------
    // bfrag values are IDENTICAL to the unswapped kernel (A/B fragment layout mirror).
    bf16x8 bfrag[4][3];
    f32x4  sbf[4];
    if (is_compute) {
        #pragma unroll
        for (int ti = 0; ti < 4; ++ti) {
            const float gsc = (ti == 2) ? (-2.0f * LOG2E) : (-LOG2E);
            const int n = ln + 16 * (wv + 4 * ti);   // gate ti, unit 16wv+ln (weight col)
            #pragma unroll
            for (int c = 0; c < 3; ++c) {
                #pragma unroll
                for (int j = 0; j < 8; ++j) {
                    int k = qd * 8 + 32 * c + j;
                    float w;
                    if (k < 64)                  w = w_hh[k * NG + n];
                    else if (k == 64 || k == 75) w = w_ih[n];
                    else if (k <= 74)            w = w_ih[(k - 64) * NG + n];
                    else                         w = 0.0f;
                    bfrag[ti][c][j] = (bf16_t)(w * gsc);
                }
            }
            // swapped C layout: lane(qd,ln) holds D[unit 16wv+qd*4+r][batch ln]
            #pragma unroll
            for (int r = 0; r < 4; ++r)
                sbf[ti][r] = sbias[ln * SBSTR + (16 * (wv + 4 * ti) + qd * 4 + r)] * gsc;
        }
    }

    // head fragments: w_out^T as A operand (same values as before), C = b_out rows
    bf16x8 wob0, wob1;
    f32x4  bC;
    #pragma unroll
    for (int j = 0; j < 8; ++j) {
        wob0[j] = (bf16_t)((ln < 2) ? w_out[(qd * 8 + j) * 2 + ln] : 0.0f);
        wob1[j] = (bf16_t)((ln < 2) ? w_out[(32 + qd * 8 + j) * 2 + ln] : 0.0f);
    }
    #pragma unroll
    for (int r = 0; r < 4; ++r)
        bC[r] = (qd == 0 && r < 2) ? b_out[r] : 0.0f;
    const float sclh = scl_s[ln];   // batch-row scale for head lane (qd==0, r==0 path)

    __syncthreads();   // all sbias/sx reads done -> safe to overwrite with pcx

    // zero pcx (both buffers; establishes the permanent-zero slots 12..15)
    for (int i = tid; i < (2 * CH * BT * PSTR) / 2; i += NT) ((int*)smemA)[i] = 0;
    __syncthreads();

    // fill pcx chunk 0 (steps 0..31)
    if (tid < 256) {
        const int row = tid >> 4, i5 = tid & 15;
        const float* cr = cov + (size_t)(b0 + row) * (SS * 10);
        #pragma unroll
        for (int j = 0; j < 20; ++j) {
            int e = i5 + 16 * j, tp = e / 10, k = e - 10 * tp;
            pcx[((0 * CH + tp) * BT + row) * PSTR + 1 + k] = f2bf(cr[e]);
        }
        float pv0 = (i5 == 0) ? 0.0f : target[(size_t)(b0 + row) * SS + i5 - 1] * inv_s[row];
        float pv1 = target[(size_t)(b0 + row) * SS + i5 + 15] * inv_s[row];
        unsigned short m0 = f2bf(pv0), m1 = f2bf(pv1);
        pcx[((0 * CH + i5) * BT + row) * PSTR + 0]       = m0;
        pcx[((0 * CH + i5) * BT + row) * PSTR + 11]      = f2bf(pv0 - bf2f(m0));
        pcx[((0 * CH + i5 + 16) * BT + row) * PSTR + 0]  = m1;
        pcx[((0 * CH + i5 + 16) * BT + row) * PSTR + 11] = f2bf(pv1 - bf2f(m1));
    }
    __syncthreads();

    // prime a2(0) and acc_pre(0) = x-part of gates^T for t=0 (compute waves)
    bf16x8 a2 = {};
    f32x4 acc_pre[4];
    if (is_compute) {
        if (qd < 2)
            a2 = *(const bf16x8*)&pcx[((0 * CH + 0) * BT + ln) * PSTR + qd * 8];
        #pragma unroll
        for (int ti = 0; ti < 4; ++ti)
            acc_pre[ti] = __builtin_amdgcn_mfma_f32_16x16x32_bf16(bfrag[ti][2], a2, sbf[ti], 0, 0, 0);
    }

    float cst[4] = {0.0f, 0.0f, 0.0f, 0.0f};   // c-state: units 16wv+qd*4+r, batch row ln
    float crg[20];
    #pragma unroll
    for (int j = 0; j < 20; ++j) crg[j] = 0.0f;
    float trg0 = 0.0f, trg1 = 0.0f;

    // ---------------- time loop (ONE lgkm-only barrier per step) ----------------
    for (int t = 0; t < SS; ++t) {
        const int cur = t & 1, nxt = cur ^ 1;
        bar_lgkm();        // hbuf[cur] complete; acc_pre already holds x-part of gates(t)

        if (is_compute) {
            // ---- recurrence waves: 2-deep swapped MFMA chain + lane-local cell ----
            const unsigned short* hb = &hbuf[cur][ln][0];
            bf16x8 a0 = *(const bf16x8*)(hb + qd * 8);
            bf16x8 a1 = *(const bf16x8*)(hb + 32 + qd * 8);

            f32x4 acc0 = __builtin_amdgcn_mfma_f32_16x16x32_bf16(bfrag[0][0], a0, acc_pre[0], 0, 0, 0);
            f32x4 acc1 = __builtin_amdgcn_mfma_f32_16x16x32_bf16(bfrag[1][0], a0, acc_pre[1], 0, 0, 0);
            f32x4 acc2 = __builtin_amdgcn_mfma_f32_16x16x32_bf16(bfrag[2][0], a0, acc_pre[2], 0, 0, 0);
            f32x4 acc3 = __builtin_amdgcn_mfma_f32_16x16x32_bf16(bfrag[3][0], a0, acc_pre[3], 0, 0, 0);
            acc0 = __builtin_amdgcn_mfma_f32_16x16x32_bf16(bfrag[0][1], a1, acc0, 0, 0, 0);
            acc1 = __builtin_amdgcn_mfma_f32_16x16x32_bf16(bfrag[1][1], a1, acc1, 0, 0, 0);
            acc2 = __builtin_amdgcn_mfma_f32_16x16x32_bf16(bfrag[2][1], a1, acc2, 0, 0, 0);
            acc3 = __builtin_amdgcn_mfma_f32_16x16x32_bf16(bfrag[3][1], a1, acc3, 0, 0, 0);

            // prefetch a2 for t+1 (pcx stable; committed >=23 steps earlier)
            if (t + 1 < SS && qd < 2)
                a2 = *(const bf16x8*)&pcx[((((t + 1) >> 5) & 1) * CH + ((t + 1) & 31)) * BT * PSTR
                                          + ln * PSTR + qd * 8];

            // lane-local LSTM cell: units 16wv+qd*4+r, batch row ln
            // acc0/1/3 = -log2e * (i,f,o preact); acc2 = -2log2e * g preact
            bf16x4 hq;
            #pragma unroll
            for (int r = 0; r < 4; ++r) {
                float si = frcp_(1.0f + fexp2_(acc0[r]));
                float sf = frcp_(1.0f + fexp2_(acc1[r]));
                float tg = 2.0f * frcp_(1.0f + fexp2_(acc2[r])) - 1.0f;
                float so = frcp_(1.0f + fexp2_(acc3[r]));
                float cc = sf * cst[r] + si * tg;
                cst[r] = cc;
                float th = 2.0f * frcp_(1.0f + fexp2_((-2.0f * LOG2E) * cc)) - 1.0f;
                hq[r] = (bf16_t)(so * th);
            }
            // 4 consecutive units of row ln -> ONE ds_write_b64
            *(bf16x4*)&hbuf[nxt][ln][16 * wv + qd * 4] = hq;

            // x-part of gates for t+1 (independent of h; executes under the barrier wait)
            if (t + 1 < SS) {
                #pragma unroll
                for (int ti = 0; ti < 4; ++ti)
                    acc_pre[ti] = __builtin_amdgcn_mfma_f32_16x16x32_bf16(bfrag[ti][2], a2, sbf[ti], 0, 0, 0);
            }
        } else {
            // ---- service waves ----
            if ((t & 31) == 0 && t < 480) {
                const int row = tid2 >> 4, i5 = tid2 & 15, t0n = t + CH;
                const float* cr = cov + (size_t)(b0 + row) * (SS * 10) + t0n * 10;
                #pragma unroll
                for (int j = 0; j < 20; ++j) crg[j] = cr[i5 + 16 * j];
                const float* tr = target + (size_t)(b0 + row) * SS + t0n + i5;
                trg0 = tr[-1];
                trg1 = tr[15];
            }

            // head for t-1 via swapped MFMA on wave 4: D[outcol][batch]
            if (wv == 4 && t > 0) {
                const unsigned short* hb = &hbuf[cur][ln][0];
                bf16x8 a0 = *(const bf16x8*)(hb + qd * 8);
                bf16x8 a1 = *(const bf16x8*)(hb + 32 + qd * 8);
                f32x4 hacc = __builtin_amdgcn_mfma_f32_16x16x32_bf16(wob0, a0, bC, 0, 0, 0);
                hacc = __builtin_amdgcn_mfma_f32_16x16x32_bf16(wob1, a1, hacc, 0, 0, 0);
                if (qd == 0) {
                    float sp0 = softplus_(hacc[0]) + 1e-4f;   // mu_s
                    float sp1 = softplus_(hacc[1]) + 1e-4f;   // alpha
                    obuf[((t - 1) >> 5) & 1][(t - 1) & 31][ln]      = sp0 * sclh;
                    obuf[((t - 1) >> 5) & 1][(t - 1) & 31][16 + ln] = sp1;
                }
            }

            if ((t & 31) == 8) {
                const int c = t >> 5;
                if (c < 15) {   // commit chunk c+1 (loads issued at t%32==0, 8 steps ago)
                    const int row = tid2 >> 4, i5 = tid2 & 15, nb = (c + 1) & 1;
                    float pv0 = trg0 * inv_s[row];
                    float pv1 = trg1 * inv_s[row];
                    unsigned short m0 = f2bf(pv0), m1 = f2bf(pv1);
                    pcx[((nb * CH + i5) * BT + row) * PSTR + 0]       = m0;
                    pcx[((nb * CH + i5) * BT + row) * PSTR + 11]      = f2bf(pv0 - bf2f(m0));
                    pcx[((nb * CH + i5 + 16) * BT + row) * PSTR + 0]  = m1;
                    pcx[((nb * CH + i5 + 16) * BT + row) * PSTR + 11] = f2bf(pv1 - bf2f(m1));
                    #pragma unroll
                    for (int j = 0; j < 20; ++j) {
                        int e = i5 + 16 * j, tp = e / 10, k = e - 10 * tp;
                        pcx[((nb * CH + tp) * BT + row) * PSTR + 1 + k] = f2bf(crg[j]);
                    }
                }
            }

            if ((t & 31) == 16) {
                const int c = t >> 5;
                if (c >= 1) {   // flush obuf chunk c-1
                    const int pb = (c - 1) & 1, t0p = (c - 1) << 5;
                    #pragma unroll
                    for (int h = 0; h < 4; ++h) {
                        int e = tid2 + 256 * h;
                        int tte = e & 31, rowe = (e >> 5) & 15, pe = e >> 9;
                        out[(pe ? (BB * SS) : 0) + (size_t)(b0 + rowe) * SS + t0p + tte] =
                            obuf[pb][tte][pe * 16 + rowe];
                    }
                }
            }
        }
    }

    // ---------------- epilogue: head for t=511 (h in hbuf[0]) + flush chunk 15 ----------------
    __syncthreads();
    if (wv == 4) {
        const unsigned short* hb = &hbuf[0][ln][0];
        bf16x8 a0 = *(const bf16x8*)(hb + qd * 8);
        bf16x8 a1 = *(const bf16x8*)(hb + 32 + qd * 8);
        f32x4 hacc = __builtin_amdgcn_mfma_f32_16x16x32_bf16(wob0, a0, bC, 0, 0, 0);
        hacc = __builtin_amdgcn_mfma_f32_16x16x32_bf16(wob1, a1, hacc, 0, 0, 0);
        if (qd == 0) {
            float sp0 = softplus_(hacc[0]) + 1e-4f;
            float sp1 = softplus_(hacc[1]) + 1e-4f;
            obuf[1][31][ln]      = sp0 * sclh;
            obuf[1][31][16 + ln] = sp1;
        }
    }
    __syncthreads();
    #pragma unroll
    for (int h = 0; h < 2; ++h) {
        int e = tid + NT * h;
        int tte = e & 31, rowe = (e >> 5) & 15, pe = e >> 9;
        out[(pe ? (BB * SS) : 0) + (size_t)(b0 + rowe) * SS + 480 + tte] =
            obuf[1][tte][pe * 16 + rowe];
    }
}

extern "C" void kernel_launch(void* const* d_in, const int* in_sizes, int n_in,
                              void* d_out, int out_size, void* d_ws, size_t ws_size,
                              hipStream_t stream) {
    deepar_kernel<<<BB / BT, NT, 0, stream>>>(
        (const float*)d_in[0], (const float*)d_in[1], (const int*)d_in[2],
        (const float*)d_in[3], (const float*)d_in[4], (const float*)d_in[5],
        (const float*)d_in[6], (const float*)d_in[7], (const float*)d_in[8],
        (const float*)d_in[9], (const float*)d_in[10], (const float*)d_in[11],
        (const float*)d_in[12], (float*)d_out);
}